// Round 7
// baseline (610.980 us; speedup 1.0000x reference)
//
#include <hip/hip_runtime.h>
#include <math.h>

#ifndef M_PI
#define M_PI 3.14159265358979323846
#endif

// ---------- constants ----------
#define HH   320
#define GG   640
#define NB   8
#define PTS  512000   // 800 * 640

// ---------- helpers ----------
__device__ __forceinline__ float bessel_i0f(float x){
  if (x < 3.75f){
    float t = (x*x) * (1.0f/(3.75f*3.75f));
    return 1.0f + t*(3.5156229f + t*(3.0899424f + t*(1.2067492f +
                 t*(0.2659732f + t*(0.0360768f + t*0.0045813f)))));
  } else {
    float t = 3.75f/x;
    float p = 0.39894228f + t*(0.01328592f + t*(0.00225319f + t*(-0.00157565f +
              t*(0.00916281f + t*(-0.02057706f + t*(0.02635537f +
              t*(-0.01647633f + t*0.00392377f)))))));
    return expf(x)*rsqrtf(x)*p;
  }
}

__device__ __forceinline__ float kbw(float d, float beta, float inv_i0b){
  float q = d * 0.33333333333333f;        // 2d/W with W=6
  float u = 1.0f - q*q;
  u = fmaxf(u, 0.0f);
  return bessel_i0f(beta * sqrtf(u)) * inv_i0b;
}

// ---------- build DFT matrices ----------
// M1[x,k] = (1/sqrt(320)) * (-1)^(x+k) * exp(+2*pi*i*x*k/320)
__global__ void build_m1(float2* __restrict__ M1){
  int idx = blockIdx.x*256 + threadIdx.x;
  if (idx >= HH*HH) return;
  int x = idx / HH, k = idx - x*HH;
  int r = (x*k) % HH;
  float ang = (float)r * (6.283185307179586f/(float)HH);
  float s, c; sincosf(ang, &s, &c);
  float sg = ((x + k) & 1) ? -0.05590169943749474f : 0.05590169943749474f;
  M1[idx] = make_float2(sg*c, sg*s);
}

// W2[k,m] = exp(-2*pi*i*k*(m-160)/640)   (640 x 320)
__global__ void build_w2(float2* __restrict__ W2){
  int idx = blockIdx.x*256 + threadIdx.x;
  if (idx >= GG*HH) return;
  int k = idx / HH, m = idx - k*HH;
  int t = (k * (m - 160)) % GG; if (t < 0) t += GG;
  float ang = (float)t * (6.283185307179586f/(float)GG);
  float s, c; sincosf(ang, &s, &c);
  W2[idx] = make_float2(c, -s);
}

// rap[n] = 1 / apod1d(n)
__global__ void build_rap(float* __restrict__ rap, float beta){
  int n = threadIdx.x;  // 320 threads
  if (n >= HH) return;
  float f = (float)(n - 160) * (1.0f/(float)GG);
  float w = 3.14159265358979f * 6.0f * f;
  float t = beta*beta - w*w;
  float z = fmaxf(sqrtf(fabsf(t)), 1e-7f);
  float a = (t > 0.0f ? sinhf(z) : sinf(z)) / z;
  float a0 = sinhf(beta) / beta;
  rap[n] = a0 / a;
}

// ---------- pack two real arrays into interleaved complex ----------
__global__ void pack_c(const float* __restrict__ re, const float* __restrict__ im,
                       float2* __restrict__ out, int n){
  int i = blockIdx.x*256 + threadIdx.x;
  if (i < n) out[i] = make_float2(re[i], im[i]);
}

// ---------- batched complex GEMM, templated tile, XCD-swizzled ----------
// TB=0 (NN): C[i,j] = sum_k A[i,k]*B[k,j]
// TB=1 (NT): C[i,j] = sum_k A[i,k]*B[j,k]
// Tile: (16*TM) x (16*TN), 256 threads, micro TM x TN. 1D grid = gx*gy*gz,
// decoded j-fastest after a bijective XCD-chunk swizzle (m204) so blocks
// sharing an A-panel co-locate on one XCD's L2.
template<int TB, int TM, int TN>
__global__ __launch_bounds__(256)
void cgemm(const float2* __restrict__ A, int lda, long abatch,
           const float2* __restrict__ B, int ldb, long bbatch,
           float2* __restrict__ C, int ldc, long cbatch,
           int K, int gx, int gy)
{
  constexpr int BMt = 16*TM, BNt = 16*TN;
  __shared__ float2 As[BMt][17];
  __shared__ float2 Bs[16][BNt+1];

  // bijective XCD swizzle: orig -> wg
  int nwg  = gridDim.x;
  int orig = blockIdx.x;
  int qn = nwg >> 3, rn = nwg & 7;
  int xcd = orig & 7, pos = orig >> 3;
  int wg = (xcd < rn ? xcd*(qn+1) : rn*(qn+1) + (xcd-rn)*qn) + pos;
  int bj = wg % gx; int t2 = wg / gx; int bi = t2 % gy; int bz = t2 / gy;

  A += (long)bz * abatch;
  B += (long)bz * bbatch;
  C += (long)bz * cbatch;
  int i0 = bi * BMt;
  int j0 = bj * BNt;
  int tid = threadIdx.x;
  int tx = tid & 15, ty = tid >> 4;

  float2 acc[TM][TN];
  #pragma unroll
  for (int r=0;r<TM;r++)
    #pragma unroll
    for (int c=0;c<TN;c++) acc[r][c] = make_float2(0.f, 0.f);

  for (int kt = 0; kt < K; kt += 16){
    // A tile: BMt x 16
    for (int i = tid>>2; i < BMt; i += 64){
      int k0 = (tid & 3) * 4;
      #pragma unroll
      for (int q=0;q<4;q++)
        As[i][k0+q] = A[(long)(i0+i)*lda + kt + k0 + q];
    }
    if (TB == 0){
      for (int j = tid & 63; j < BNt; j += 64){
        #pragma unroll
        for (int r=0;r<4;r++){
          int kk = (tid >> 6) + r*4;
          Bs[kk][j] = B[(long)(kt+kk)*ldb + j0 + j];
        }
      }
    } else {
      for (int j = tid>>2; j < BNt; j += 64){
        int k0 = (tid & 3) * 4;
        #pragma unroll
        for (int q=0;q<4;q++)
          Bs[k0+q][j] = B[(long)(j0+j)*ldb + kt + k0 + q];
      }
    }
    __syncthreads();

    #pragma unroll
    for (int kk=0;kk<16;kk++){
      float2 a[TM], bv[TN];
      #pragma unroll
      for (int r=0;r<TM;r++) a[r] = As[ty + r*16][kk];
      #pragma unroll
      for (int c=0;c<TN;c++) bv[c] = Bs[kk][tx + c*16];
      #pragma unroll
      for (int r=0;r<TM;r++)
        #pragma unroll
        for (int c=0;c<TN;c++){
          acc[r][c].x = fmaf(a[r].x, bv[c].x, fmaf(-a[r].y, bv[c].y, acc[r][c].x));
          acc[r][c].y = fmaf(a[r].x, bv[c].y, fmaf( a[r].y, bv[c].x, acc[r][c].y));
        }
    }
    __syncthreads();
  }

  #pragma unroll
  for (int r=0;r<TM;r++)
    #pragma unroll
    for (int c=0;c<TN;c++){
      int i = i0 + ty + r*16;
      int j = j0 + tx + c*16;
      C[(long)i*ldc + j] = acc[r][c];
    }
}

// ---------- per-slice mean/std, stage 1: 32 segments/slice partial sums ----------
__global__ void stats_part(const float2* __restrict__ img, double* __restrict__ part){
  int slice = blockIdx.y, seg = blockIdx.x;   // 8 x 32
  const float2* p = img + (long)slice*(HH*HH) + (long)seg*3200;
  double sr=0.0, si=0.0, srr=0.0, sii=0.0;
  for (int i = threadIdx.x; i < 3200; i += 256){
    float2 v = p[i];
    sr += (double)v.x; si += (double)v.y;
    srr += (double)v.x*(double)v.x; sii += (double)v.y*(double)v.y;
  }
  __shared__ double sh[256];
  double vals[4] = {sr, si, srr, sii};
  #pragma unroll
  for (int q=0;q<4;q++){
    sh[threadIdx.x] = vals[q];
    __syncthreads();
    for (int s=128; s>0; s>>=1){
      if (threadIdx.x < s) sh[threadIdx.x] += sh[threadIdx.x + s];
      __syncthreads();
    }
    if (threadIdx.x == 0) part[((long)slice*32 + seg)*4 + q] = sh[0];
    __syncthreads();
  }
}

// ---------- stage 2: finish (ddof=1) ----------
__global__ void stats_fin(const double* __restrict__ part, float4* __restrict__ stats){
  int b = blockIdx.x;
  int t = threadIdx.x;  // 64
  __shared__ double sh[64];
  double red[4];
  #pragma unroll
  for (int q=0;q<4;q++){
    sh[t] = (t < 32) ? part[((long)b*32 + t)*4 + q] : 0.0;
    __syncthreads();
    for (int s=32; s>0; s>>=1){
      if (t < s) sh[t] += sh[t + s];
      __syncthreads();
    }
    red[q] = sh[0];
    __syncthreads();
  }
  if (t == 0){
    double N = (double)(HH*HH);
    double mr = red[0]/N, mi = red[1]/N;
    double vr = (red[2] - N*mr*mr)/(N-1.0);
    double vi = (red[3] - N*mi*mi)/(N-1.0);
    stats[b] = make_float4((float)mr, (float)mi,
                           (float)(1.0/sqrt(vr)), (float)(1.0/sqrt(vi)));
  }
}

// ---------- normalization + apodization divide (in-place) ----------
__global__ void norm_apod(const float2* img, const float4* __restrict__ stats,
                          const float* __restrict__ rap, float2* xn){
  int idx = blockIdx.x*256 + threadIdx.x;  // 8*320*320
  if (idx >= NB*HH*HH) return;
  int b = idx / (HH*HH), rem = idx - b*(HH*HH);
  int i = rem / HH, j = rem - i*HH;
  float4 st = stats[b];
  float2 v = img[idx];
  float sc = rap[i]*rap[j];
  xn[idx] = make_float2((v.x - st.x)*st.z*sc, (v.y - st.y)*st.w*sc);
}

// ---------- KB interpolation gather, row-split, PLANAR Xos [s][kx][ky] ----------
// Block = 384 threads = 6 waves x 64 points; wave w = KB row jx=w.
template<int NC>
__global__ __launch_bounds__(384)
void interp6(const float* __restrict__ tkx, const float* __restrict__ tky,
             const float2* __restrict__ Xos, float* __restrict__ out,
             int slice0, int cplx, float beta, float inv_i0b){
  __shared__ float2 sh[NC][6][64];
  int tid = threadIdx.x;
  int ptl = tid & 63;          // point within block (lane)
  int jx  = tid >> 6;          // KB row index = wave index
  int p   = blockIdx.x*64 + ptl;   // 8000 blocks * 64 = 512000 exactly

  float gx = tkx[p]*2.0f, gy = tky[p]*2.0f;
  int ix0 = (int)floorf(gx) - 2;
  int iy0 = (int)floorf(gy) - 2;

  int ixu = ix0 + jx;
  int ixm = (ixu < 0) ? ixu + GG : ((ixu >= GG) ? ixu - GG : ixu);
  float wxj = kbw(gx - (float)ixu, beta, inv_i0b);

  float wy[6]; int iym[6];
  #pragma unroll
  for (int j=0;j<6;j++){
    int iyu = iy0 + j;
    wy[j] = kbw(gy - (float)iyu, beta, inv_i0b);
    iym[j] = (iyu < 0) ? iyu + GG : ((iyu >= GG) ? iyu - GG : iyu);
  }

  float2 acc[NC];
  #pragma unroll
  for (int s=0;s<NC;s++) acc[s] = make_float2(0.f, 0.f);

  long rowbase = (long)ixm*GG;
  #pragma unroll
  for (int jy=0;jy<6;jy++){
    float w = wy[jy];
    long off = rowbase + iym[jy];
    #pragma unroll
    for (int s=0;s<NC;s++){
      float2 v = Xos[(long)s*(GG*GG) + off];
      acc[s].x = fmaf(w, v.x, acc[s].x);
      acc[s].y = fmaf(w, v.y, acc[s].y);
    }
  }
  // scale by this thread's wx and stash partial (lanes contiguous: conflict-free)
  #pragma unroll
  for (int s=0;s<NC;s++)
    sh[s][jx][ptl] = make_float2(acc[s].x*wxj, acc[s].y*wxj);
  __syncthreads();

  // reduce 6 rows per (point, slice)
  for (int t2 = tid; t2 < 64*NC; t2 += 384){
    int pt = t2 / NC;
    int s  = t2 - pt*NC;
    float2 r = make_float2(0.f, 0.f);
    #pragma unroll
    for (int j=0;j<6;j++){
      float2 v = sh[s][j][pt];
      r.x += v.x; r.y += v.y;
    }
    long pg = (long)blockIdx.x*64 + pt;
    if (cplx){
      ((float2*)out)[(long)(slice0+s)*PTS + pg] = r;
    } else {
      out[(long)(slice0+s)*PTS + pg] = r.x;
    }
  }
}

// ---------- launch ----------
extern "C" void kernel_launch(void* const* d_in, const int* in_sizes, int n_in,
                              void* d_out, int out_size, void* d_ws, size_t ws_size,
                              hipStream_t stream) {
  const float* kr  = (const float*)d_in[0];
  const float* ki  = (const float*)d_in[1];
  const float* tkx = (const float*)d_in[2];
  const float* tky = (const float*)d_in[3];
  char* ws = (char*)d_ws;

  // ---- fixed workspace layout ----
  float2* M1    = (float2*)(ws + 0);          //   819,200 B
  float2* W2    = (float2*)(ws + 819200);     // 1,638,400 B -> 2,457,600
  float*  rap   = (float*) (ws + 2457600);    //     1,280 B -> 2,458,880
  float4* stats = (float4*)(ws + 2458880);    //       128 B -> 2,459,008
  double* part  = (double*)(ws + 2459008);    //     8,192 B -> 2,467,200
  float2* P     = (float2*)(ws + 2467200);    // 6,553,600 B -> 9,020,800  (Kc -> image -> xn)
  float2* Q     = (float2*)(ws + 9020800);    // 6,553,600 B (Trow; dead after GEMM2)
  const long base = 9020800;

  // ---- choose slice chunk size nc from actual ws_size (call-invariant) ----
  int nc = 1;
  if      (ws_size >= (size_t)(base + 8L*4915200)) nc = 8;   // 48,342,400
  else if (ws_size >= (size_t)(base + 4L*4915200)) nc = 4;   // 28,681,600
  else if (ws_size >= (size_t)(base + 2L*4915200)) nc = 2;   // 18,851,200
  if (ws_size < (size_t)(base + 4915200)) return;            // < 13.94 MB: fail clean

  float2* U   = (float2*)(ws + base);                        // nc * 1,638,400 B
  float2* Xos = (float2*)(ws + base + (long)nc*1638400);     // nc * 3,276,800 B (planar [s][kx][ky])

  int cplx = (out_size >= 8192000) ? 1 : 0;

  // host-side constants (pure CPU math; graph-capture safe)
  double beta_d = M_PI * sqrt(9.0*2.25 - 0.8);
  double qq = beta_d*beta_d/4.0, term = 1.0, i0b = 1.0;
  for (int k=1;k<64;k++){ term *= qq/((double)k*(double)k); i0b += term; }
  float beta = (float)beta_d;
  float inv_i0b = (float)(1.0/i0b);

  build_m1 <<<400, 256, 0, stream>>>(M1);
  build_w2 <<<800, 256, 0, stream>>>(W2);
  build_rap<<<1,   320, 0, stream>>>(rap, beta);
  pack_c   <<<3200,256, 0, stream>>>(kr, ki, P, NB*HH*HH);

  // Q[b] = Kc[b] (320x320) * M1^T      grid (gx=5, gy=5, gz=8) -> 200 blocks
  cgemm<1,4,4><<<200, 256, 0, stream>>>(P,320,102400, M1,320,0,
                                        Q,320,102400, 320, 5,5);
  // P[b] = M1 * Q[b]
  cgemm<0,4,4><<<200, 256, 0, stream>>>(M1,320,0, Q,320,102400,
                                        P,320,102400, 320, 5,5);
  stats_part<<<dim3(32,NB), 256, 0, stream>>>(P, part);
  stats_fin <<<NB, 64, 0, stream>>>(part, stats);
  norm_apod <<<3200, 256, 0, stream>>>(P, stats, rap, P);   // in-place

  // oversampled DFT + gather, nc slices per chunk (U/Xos overlay Q region)
  for (int c = 0; c < NB/nc; ++c){
    // U[s] = W2 (640x320) * xn[c*nc+s]     grid (gx=5, gy=10, gz=nc)
    cgemm<0,4,4><<<50*nc, 256, 0, stream>>>(W2,320,0, P + (long)c*nc*102400,320,102400,
                                            U,320,204800, 320, 5,10);
    // Xos[s][kx][ky] = sum_my U[s,kx,my] * W2[ky,my]   grid (gx=5, gy=10, gz=nc), tile 64x128
    cgemm<1,4,8><<<50*nc, 256, 0, stream>>>(U,320,204800, W2,320,0,
                                            Xos,640,409600, 320, 5,10);
    switch (nc){
      case 8: interp6<8><<<8000,384,0,stream>>>(tkx,tky,Xos,(float*)d_out, c*8, cplx, beta, inv_i0b); break;
      case 4: interp6<4><<<8000,384,0,stream>>>(tkx,tky,Xos,(float*)d_out, c*4, cplx, beta, inv_i0b); break;
      case 2: interp6<2><<<8000,384,0,stream>>>(tkx,tky,Xos,(float*)d_out, c*2, cplx, beta, inv_i0b); break;
      default: interp6<1><<<8000,384,0,stream>>>(tkx,tky,Xos,(float*)d_out, c,   cplx, beta, inv_i0b); break;
    }
  }
}

// Round 8
// 608.153 us; speedup vs baseline: 1.0046x; 1.0046x over previous
//
#include <hip/hip_runtime.h>
#include <math.h>

#ifndef M_PI
#define M_PI 3.14159265358979323846
#endif

// ---------- constants ----------
#define HH   320
#define GG   640
#define NB   8
#define PTS  512000   // 800 * 640

// ---------- helpers ----------
__device__ __forceinline__ float bessel_i0f(float x){
  if (x < 3.75f){
    float t = (x*x) * (1.0f/(3.75f*3.75f));
    return 1.0f + t*(3.5156229f + t*(3.0899424f + t*(1.2067492f +
                 t*(0.2659732f + t*(0.0360768f + t*0.0045813f)))));
  } else {
    float t = 3.75f/x;
    float p = 0.39894228f + t*(0.01328592f + t*(0.00225319f + t*(-0.00157565f +
              t*(0.00916281f + t*(-0.02057706f + t*(0.02635537f +
              t*(-0.01647633f + t*0.00392377f)))))));
    return expf(x)*rsqrtf(x)*p;
  }
}

__device__ __forceinline__ float kbw(float d, float beta, float inv_i0b){
  float q = d * 0.33333333333333f;        // 2d/W with W=6
  float u = 1.0f - q*q;
  u = fmaxf(u, 0.0f);
  return bessel_i0f(beta * sqrtf(u)) * inv_i0b;
}

// ---------- build DFT matrices ----------
__global__ void build_m1(float2* __restrict__ M1){
  int idx = blockIdx.x*256 + threadIdx.x;
  if (idx >= HH*HH) return;
  int x = idx / HH, k = idx - x*HH;
  int r = (x*k) % HH;
  float ang = (float)r * (6.283185307179586f/(float)HH);
  float s, c; sincosf(ang, &s, &c);
  float sg = ((x + k) & 1) ? -0.05590169943749474f : 0.05590169943749474f;
  M1[idx] = make_float2(sg*c, sg*s);
}

__global__ void build_w2(float2* __restrict__ W2){
  int idx = blockIdx.x*256 + threadIdx.x;
  if (idx >= GG*HH) return;
  int k = idx / HH, m = idx - k*HH;
  int t = (k * (m - 160)) % GG; if (t < 0) t += GG;
  float ang = (float)t * (6.283185307179586f/(float)GG);
  float s, c; sincosf(ang, &s, &c);
  W2[idx] = make_float2(c, -s);
}

__global__ void build_rap(float* __restrict__ rap, float beta){
  int n = threadIdx.x;  // 320 threads
  if (n >= HH) return;
  float f = (float)(n - 160) * (1.0f/(float)GG);
  float w = 3.14159265358979f * 6.0f * f;
  float t = beta*beta - w*w;
  float z = fmaxf(sqrtf(fabsf(t)), 1e-7f);
  float a = (t > 0.0f ? sinhf(z) : sinf(z)) / z;
  float a0 = sinhf(beta) / beta;
  rap[n] = a0 / a;
}

__global__ void pack_c(const float* __restrict__ re, const float* __restrict__ im,
                       float2* __restrict__ out, int n){
  int i = blockIdx.x*256 + threadIdx.x;
  if (i < n) out[i] = make_float2(re[i], im[i]);
}

// ---------- generic complex GEMM (GEMM1/2/3), XCD-swizzled ----------
template<int TB, int TM, int TN>
__global__ __launch_bounds__(256)
void cgemm(const float2* __restrict__ A, int lda, long abatch,
           const float2* __restrict__ B, int ldb, long bbatch,
           float2* __restrict__ C, int ldc, long cbatch,
           int K, int gx, int gy)
{
  constexpr int BMt = 16*TM, BNt = 16*TN;
  __shared__ float2 As[BMt][17];
  __shared__ float2 Bs[16][BNt+1];

  int nwg  = gridDim.x;
  int orig = blockIdx.x;
  int qn = nwg >> 3, rn = nwg & 7;
  int xcd = orig & 7, pos = orig >> 3;
  int wg = (xcd < rn ? xcd*(qn+1) : rn*(qn+1) + (xcd-rn)*qn) + pos;
  int bj = wg % gx; int t2 = wg / gx; int bi = t2 % gy; int bz = t2 / gy;

  A += (long)bz * abatch;
  B += (long)bz * bbatch;
  C += (long)bz * cbatch;
  int i0 = bi * BMt;
  int j0 = bj * BNt;
  int tid = threadIdx.x;
  int tx = tid & 15, ty = tid >> 4;

  float2 acc[TM][TN];
  #pragma unroll
  for (int r=0;r<TM;r++)
    #pragma unroll
    for (int c=0;c<TN;c++) acc[r][c] = make_float2(0.f, 0.f);

  for (int kt = 0; kt < K; kt += 16){
    for (int i = tid>>2; i < BMt; i += 64){
      int k0 = (tid & 3) * 4;
      #pragma unroll
      for (int q=0;q<4;q++)
        As[i][k0+q] = A[(long)(i0+i)*lda + kt + k0 + q];
    }
    if (TB == 0){
      for (int j = tid & 63; j < BNt; j += 64){
        #pragma unroll
        for (int r=0;r<4;r++){
          int kk = (tid >> 6) + r*4;
          Bs[kk][j] = B[(long)(kt+kk)*ldb + j0 + j];
        }
      }
    } else {
      for (int j = tid>>2; j < BNt; j += 64){
        int k0 = (tid & 3) * 4;
        #pragma unroll
        for (int q=0;q<4;q++)
          Bs[k0+q][j] = B[(long)(j0+j)*ldb + kt + k0 + q];
      }
    }
    __syncthreads();

    #pragma unroll
    for (int kk=0;kk<16;kk++){
      float2 a[TM], bv[TN];
      #pragma unroll
      for (int r=0;r<TM;r++) a[r] = As[ty + r*16][kk];
      #pragma unroll
      for (int c=0;c<TN;c++) bv[c] = Bs[kk][tx + c*16];
      #pragma unroll
      for (int r=0;r<TM;r++)
        #pragma unroll
        for (int c=0;c<TN;c++){
          acc[r][c].x = fmaf(a[r].x, bv[c].x, fmaf(-a[r].y, bv[c].y, acc[r][c].x));
          acc[r][c].y = fmaf(a[r].x, bv[c].y, fmaf( a[r].y, bv[c].x, acc[r][c].y));
        }
    }
    __syncthreads();
  }

  #pragma unroll
  for (int r=0;r<TM;r++)
    #pragma unroll
    for (int c=0;c<TN;c++){
      int i = i0 + ty + r*16;
      int j = j0 + tx + c*16;
      C[(long)i*ldc + j] = acc[r][c];
    }
}

// ---------- GEMM4: all NC slices per block, interleaved dense writes ----------
// Xos[(kx*640+ky)*NC + s] = sum_k U[s][kx][k] * W2[ky][k]
// Tile 64(kx) x 32(ky) x NC. Grid 10*20=200 blocks (XCD-swizzled).
template<int NC>
__global__ __launch_bounds__(256)
void cgemm4(const float2* __restrict__ U,   // [NC][640][320]
            const float2* __restrict__ W2,  // [640][320]
            float2* __restrict__ Xos)
{
  __shared__ float2 As[NC][64][17];
  __shared__ float2 Bs[16][33];

  int nwg = gridDim.x, orig = blockIdx.x;
  int qn = nwg>>3, rn = nwg&7;
  int xcd = orig&7, pos = orig>>3;
  int wg = (xcd<rn ? xcd*(qn+1) : rn*(qn+1)+(xcd-rn)*qn) + pos;
  int bj = wg % 20, bi = wg / 20;
  int i0 = bi*64, j0 = bj*32;
  int tid = threadIdx.x, tx = tid&15, ty = tid>>4;

  float2 acc[NC][4][2];
  #pragma unroll
  for (int s=0;s<NC;s++)
    #pragma unroll
    for (int r=0;r<4;r++)
      #pragma unroll
      for (int c=0;c<2;c++) acc[s][r][c] = make_float2(0.f,0.f);

  for (int kt = 0; kt < 320; kt += 16){
    { // A: NC x 64 x 16
      int i = tid>>2, k0 = (tid&3)*4;
      #pragma unroll
      for (int s=0;s<NC;s++)
        #pragma unroll
        for (int q=0;q<4;q++)
          As[s][i][k0+q] = U[(long)s*204800 + (long)(i0+i)*320 + kt + k0 + q];
    }
    { // B (NT): Bs[k][j] = W2[(j0+j)*320 + kt+k]
      int j = tid>>3, k0 = (tid&7)*2;
      Bs[k0  ][j] = W2[(long)(j0+j)*320 + kt + k0];
      Bs[k0+1][j] = W2[(long)(j0+j)*320 + kt + k0 + 1];
    }
    __syncthreads();

    #pragma unroll
    for (int kk=0;kk<16;kk++){
      float2 b0 = Bs[kk][tx], b1 = Bs[kk][tx+16];
      #pragma unroll
      for (int s=0;s<NC;s++){
        #pragma unroll
        for (int r=0;r<4;r++){
          float2 a = As[s][ty + r*16][kk];
          acc[s][r][0].x = fmaf(a.x, b0.x, fmaf(-a.y, b0.y, acc[s][r][0].x));
          acc[s][r][0].y = fmaf(a.x, b0.y, fmaf( a.y, b0.x, acc[s][r][0].y));
          acc[s][r][1].x = fmaf(a.x, b1.x, fmaf(-a.y, b1.y, acc[s][r][1].x));
          acc[s][r][1].y = fmaf(a.x, b1.y, fmaf( a.y, b1.x, acc[s][r][1].y));
        }
      }
    }
    __syncthreads();
  }

  #pragma unroll
  for (int r=0;r<4;r++)
    #pragma unroll
    for (int c=0;c<2;c++){
      int i = i0 + ty + r*16;
      int j = j0 + tx + c*16;
      float2* dst = Xos + ((long)i*GG + j)*NC;
      #pragma unroll
      for (int s=0;s<NC;s++) dst[s] = acc[s][r][c];
    }
}

// ---------- per-slice mean/std, stage 1 ----------
__global__ void stats_part(const float2* __restrict__ img, double* __restrict__ part){
  int slice = blockIdx.y, seg = blockIdx.x;   // 8 x 32
  const float2* p = img + (long)slice*(HH*HH) + (long)seg*3200;
  double sr=0.0, si=0.0, srr=0.0, sii=0.0;
  for (int i = threadIdx.x; i < 3200; i += 256){
    float2 v = p[i];
    sr += (double)v.x; si += (double)v.y;
    srr += (double)v.x*(double)v.x; sii += (double)v.y*(double)v.y;
  }
  __shared__ double sh[256];
  double vals[4] = {sr, si, srr, sii};
  #pragma unroll
  for (int q=0;q<4;q++){
    sh[threadIdx.x] = vals[q];
    __syncthreads();
    for (int s=128; s>0; s>>=1){
      if (threadIdx.x < s) sh[threadIdx.x] += sh[threadIdx.x + s];
      __syncthreads();
    }
    if (threadIdx.x == 0) part[((long)slice*32 + seg)*4 + q] = sh[0];
    __syncthreads();
  }
}

// ---------- stage 2: finish (ddof=1) ----------
__global__ void stats_fin(const double* __restrict__ part, float4* __restrict__ stats){
  int b = blockIdx.x;
  int t = threadIdx.x;  // 64
  __shared__ double sh[64];
  double red[4];
  #pragma unroll
  for (int q=0;q<4;q++){
    sh[t] = (t < 32) ? part[((long)b*32 + t)*4 + q] : 0.0;
    __syncthreads();
    for (int s=32; s>0; s>>=1){
      if (t < s) sh[t] += sh[t + s];
      __syncthreads();
    }
    red[q] = sh[0];
    __syncthreads();
  }
  if (t == 0){
    double N = (double)(HH*HH);
    double mr = red[0]/N, mi = red[1]/N;
    double vr = (red[2] - N*mr*mr)/(N-1.0);
    double vi = (red[3] - N*mi*mi)/(N-1.0);
    stats[b] = make_float4((float)mr, (float)mi,
                           (float)(1.0/sqrt(vr)), (float)(1.0/sqrt(vi)));
  }
}

// ---------- normalization + apodization divide (in-place) ----------
__global__ void norm_apod(const float2* img, const float4* __restrict__ stats,
                          const float* __restrict__ rap, float2* xn){
  int idx = blockIdx.x*256 + threadIdx.x;  // 8*320*320
  if (idx >= NB*HH*HH) return;
  int b = idx / (HH*HH), rem = idx - b*(HH*HH);
  int i = rem / HH, j = rem - i*HH;
  float4 st = stats[b];
  float2 v = img[idx];
  float sc = rap[i]*rap[j];
  xn[idx] = make_float2((v.x - st.x)*st.z*sc, (v.y - st.y)*st.w*sc);
}

// ---------- KB gather, row-split, INTERLEAVED Xos [kx][ky][s] ----------
// Block = 384 threads = 6 waves x 64 points; wave w = KB row jx=w.
template<int NC>
__global__ __launch_bounds__(384)
void interp6(const float* __restrict__ tkx, const float* __restrict__ tky,
             const float2* __restrict__ Xos, float* __restrict__ out,
             int slice0, int cplx, float beta, float inv_i0b){
  __shared__ float2 sh[NC][6][64];
  int tid = threadIdx.x;
  int ptl = tid & 63;
  int jx  = tid >> 6;
  int p   = blockIdx.x*64 + ptl;   // 8000 blocks * 64 = 512000 exactly

  float gx = tkx[p]*2.0f, gy = tky[p]*2.0f;
  int ix0 = (int)floorf(gx) - 2;
  int iy0 = (int)floorf(gy) - 2;

  int ixu = ix0 + jx;
  int ixm = (ixu < 0) ? ixu + GG : ((ixu >= GG) ? ixu - GG : ixu);
  float wxj = kbw(gx - (float)ixu, beta, inv_i0b);

  float wy[6]; int iym[6];
  #pragma unroll
  for (int j=0;j<6;j++){
    int iyu = iy0 + j;
    wy[j] = kbw(gy - (float)iyu, beta, inv_i0b);
    iym[j] = (iyu < 0) ? iyu + GG : ((iyu >= GG) ? iyu - GG : iyu);
  }

  float2 acc[NC];
  #pragma unroll
  for (int s=0;s<NC;s++) acc[s] = make_float2(0.f, 0.f);

  const float2* rowp = Xos + (long)ixm*(GG*NC);
  #pragma unroll
  for (int jy=0;jy<6;jy++){
    float w = wy[jy];
    const float2* s2 = rowp + iym[jy]*NC;
    if (NC % 2 == 0){
      const float4* s4 = (const float4*)s2;
      #pragma unroll
      for (int q=0;q<NC/2;q++){
        float4 v = s4[q];
        acc[2*q  ].x = fmaf(w, v.x, acc[2*q  ].x);
        acc[2*q  ].y = fmaf(w, v.y, acc[2*q  ].y);
        acc[2*q+1].x = fmaf(w, v.z, acc[2*q+1].x);
        acc[2*q+1].y = fmaf(w, v.w, acc[2*q+1].y);
      }
    } else {
      float2 v = s2[0];
      acc[0].x = fmaf(w, v.x, acc[0].x);
      acc[0].y = fmaf(w, v.y, acc[0].y);
    }
  }
  #pragma unroll
  for (int s=0;s<NC;s++)
    sh[s][jx][ptl] = make_float2(acc[s].x*wxj, acc[s].y*wxj);
  __syncthreads();

  // reduce: pt-fastest indexing (consecutive lanes -> consecutive addresses)
  for (int t2 = tid; t2 < 64*NC; t2 += 384){
    int pt = t2 & 63;
    int s  = t2 >> 6;
    float2 r = make_float2(0.f, 0.f);
    #pragma unroll
    for (int j=0;j<6;j++){
      float2 v = sh[s][j][pt];
      r.x += v.x; r.y += v.y;
    }
    long pg = (long)blockIdx.x*64 + pt;
    if (cplx){
      ((float2*)out)[(long)(slice0+s)*PTS + pg] = r;
    } else {
      out[(long)(slice0+s)*PTS + pg] = r.x;
    }
  }
}

// ---------- launch ----------
extern "C" void kernel_launch(void* const* d_in, const int* in_sizes, int n_in,
                              void* d_out, int out_size, void* d_ws, size_t ws_size,
                              hipStream_t stream) {
  const float* kr  = (const float*)d_in[0];
  const float* ki  = (const float*)d_in[1];
  const float* tkx = (const float*)d_in[2];
  const float* tky = (const float*)d_in[3];
  char* ws = (char*)d_ws;

  // ---- fixed workspace layout ----
  float2* M1    = (float2*)(ws + 0);          //   819,200 B
  float2* W2    = (float2*)(ws + 819200);     // 1,638,400 B -> 2,457,600
  float*  rap   = (float*) (ws + 2457600);    //     1,280 B -> 2,458,880
  float4* stats = (float4*)(ws + 2458880);    //       128 B -> 2,459,008
  double* part  = (double*)(ws + 2459008);    //     8,192 B -> 2,467,200
  float2* P     = (float2*)(ws + 2467200);    // 6,553,600 B -> 9,020,800  (Kc -> image -> xn)
  const long base = 9020800;                  // Q/U/Xos region beyond

  // ---- choose slice chunk size nc from actual ws_size (call-invariant, cap 4) ----
  int nc = 1;
  if      (ws_size >= (size_t)(base + 4L*4915200)) nc = 4;   // 28,681,600
  else if (ws_size >= (size_t)(base + 2L*4915200)) nc = 2;   // 18,851,200
  if (ws_size < (size_t)(base + 4915200)) return;            // fail clean

  float2* Q   = (float2*)(ws + base);                        // GEMM1/2 temp (6.55 MB)
  float2* U   = (float2*)(ws + base);                        // nc * 1,638,400 B
  float2* Xos = (float2*)(ws + base + (long)nc*1638400);     // nc * 3,276,800 B (interleaved)

  int cplx = (out_size >= 8192000) ? 1 : 0;

  // host-side constants
  double beta_d = M_PI * sqrt(9.0*2.25 - 0.8);
  double qq = beta_d*beta_d/4.0, term = 1.0, i0b = 1.0;
  for (int k=1;k<64;k++){ term *= qq/((double)k*(double)k); i0b += term; }
  float beta = (float)beta_d;
  float inv_i0b = (float)(1.0/i0b);

  build_m1 <<<400, 256, 0, stream>>>(M1);
  build_w2 <<<800, 256, 0, stream>>>(W2);
  build_rap<<<1,   320, 0, stream>>>(rap, beta);
  pack_c   <<<3200,256, 0, stream>>>(kr, ki, P, NB*HH*HH);

  // Q[b] = Kc[b] * M1^T   (grid gx=5, gy=5, gz=8)
  cgemm<1,4,4><<<200, 256, 0, stream>>>(P,320,102400, M1,320,0,
                                        Q,320,102400, 320, 5,5);
  // P[b] = M1 * Q[b]
  cgemm<0,4,4><<<200, 256, 0, stream>>>(M1,320,0, Q,320,102400,
                                        P,320,102400, 320, 5,5);
  stats_part<<<dim3(32,NB), 256, 0, stream>>>(P, part);
  stats_fin <<<NB, 64, 0, stream>>>(part, stats);
  norm_apod <<<3200, 256, 0, stream>>>(P, stats, rap, P);   // in-place

  for (int c = 0; c < NB/nc; ++c){
    // U[s] = W2 (640x320) * xn[c*nc+s]   (grid gx=5, gy=10, gz=nc)
    cgemm<0,4,4><<<50*nc, 256, 0, stream>>>(W2,320,0, P + (long)c*nc*102400,320,102400,
                                            U,320,204800, 320, 5,10);
    // Xos[kx][ky][s] (interleaved), all nc slices per block
    switch (nc){
      case 4: cgemm4<4><<<200,256,0,stream>>>(U, W2, Xos);
              interp6<4><<<8000,384,0,stream>>>(tkx,tky,Xos,(float*)d_out, c*4, cplx, beta, inv_i0b); break;
      case 2: cgemm4<2><<<200,256,0,stream>>>(U, W2, Xos);
              interp6<2><<<8000,384,0,stream>>>(tkx,tky,Xos,(float*)d_out, c*2, cplx, beta, inv_i0b); break;
      default: cgemm4<1><<<200,256,0,stream>>>(U, W2, Xos);
              interp6<1><<<8000,384,0,stream>>>(tkx,tky,Xos,(float*)d_out, c,   cplx, beta, inv_i0b); break;
    }
  }
}

// Round 9
// 486.030 us; speedup vs baseline: 1.2571x; 1.2513x over previous
//
#include <hip/hip_runtime.h>
#include <math.h>

#ifndef M_PI
#define M_PI 3.14159265358979323846
#endif

// ---------- constants ----------
#define HH   320
#define GG   640
#define NB   8
#define PTS  512000   // 800 * 640

// ---------- helpers ----------
__device__ __forceinline__ float bessel_i0f(float x){
  if (x < 3.75f){
    float t = (x*x) * (1.0f/(3.75f*3.75f));
    return 1.0f + t*(3.5156229f + t*(3.0899424f + t*(1.2067492f +
                 t*(0.2659732f + t*(0.0360768f + t*0.0045813f)))));
  } else {
    float t = 3.75f/x;
    float p = 0.39894228f + t*(0.01328592f + t*(0.00225319f + t*(-0.00157565f +
              t*(0.00916281f + t*(-0.02057706f + t*(0.02635537f +
              t*(-0.01647633f + t*0.00392377f)))))));
    return expf(x)*rsqrtf(x)*p;
  }
}

__device__ __forceinline__ float kbw(float d, float beta, float inv_i0b){
  float q = d * 0.33333333333333f;        // 2d/W with W=6
  float u = 1.0f - q*q;
  u = fmaxf(u, 0.0f);
  return bessel_i0f(beta * sqrtf(u)) * inv_i0b;
}

// pack float2 -> complex bf16 (re low16, im high16), round-to-nearest-even
__device__ __forceinline__ unsigned pkbf(float2 v){
  unsigned a = __float_as_uint(v.x);
  a = (a + 0x7fffu + ((a>>16)&1u)) >> 16;
  unsigned b = __float_as_uint(v.y);
  b = (b + 0x7fffu + ((b>>16)&1u)) & 0xffff0000u;
  return a | b;
}

// ---------- build DFT matrices ----------
__global__ void build_m1(float2* __restrict__ M1){
  int idx = blockIdx.x*256 + threadIdx.x;
  if (idx >= HH*HH) return;
  int x = idx / HH, k = idx - x*HH;
  int r = (x*k) % HH;
  float ang = (float)r * (6.283185307179586f/(float)HH);
  float s, c; sincosf(ang, &s, &c);
  float sg = ((x + k) & 1) ? -0.05590169943749474f : 0.05590169943749474f;
  M1[idx] = make_float2(sg*c, sg*s);
}

__global__ void build_w2(float2* __restrict__ W2){
  int idx = blockIdx.x*256 + threadIdx.x;
  if (idx >= GG*HH) return;
  int k = idx / HH, m = idx - k*HH;
  int t = (k * (m - 160)) % GG; if (t < 0) t += GG;
  float ang = (float)t * (6.283185307179586f/(float)GG);
  float s, c; sincosf(ang, &s, &c);
  W2[idx] = make_float2(c, -s);
}

__global__ void build_rap(float* __restrict__ rap, float beta){
  int n = threadIdx.x;  // 320 threads
  if (n >= HH) return;
  float f = (float)(n - 160) * (1.0f/(float)GG);
  float w = 3.14159265358979f * 6.0f * f;
  float t = beta*beta - w*w;
  float z = fmaxf(sqrtf(fabsf(t)), 1e-7f);
  float a = (t > 0.0f ? sinhf(z) : sinf(z)) / z;
  float a0 = sinhf(beta) / beta;
  rap[n] = a0 / a;
}

__global__ void pack_c(const float* __restrict__ re, const float* __restrict__ im,
                       float2* __restrict__ out, int n){
  int i = blockIdx.x*256 + threadIdx.x;
  if (i < n) out[i] = make_float2(re[i], im[i]);
}

// ---------- generic complex GEMM (GEMM1/2/3), XCD-swizzled ----------
template<int TB, int TM, int TN>
__global__ __launch_bounds__(256)
void cgemm(const float2* __restrict__ A, int lda, long abatch,
           const float2* __restrict__ B, int ldb, long bbatch,
           float2* __restrict__ C, int ldc, long cbatch,
           int K, int gx, int gy)
{
  constexpr int BMt = 16*TM, BNt = 16*TN;
  __shared__ float2 As[BMt][17];
  __shared__ float2 Bs[16][BNt+1];

  int nwg  = gridDim.x;
  int orig = blockIdx.x;
  int qn = nwg >> 3, rn = nwg & 7;
  int xcd = orig & 7, pos = orig >> 3;
  int wg = (xcd < rn ? xcd*(qn+1) : rn*(qn+1) + (xcd-rn)*qn) + pos;
  int bj = wg % gx; int t2 = wg / gx; int bi = t2 % gy; int bz = t2 / gy;

  A += (long)bz * abatch;
  B += (long)bz * bbatch;
  C += (long)bz * cbatch;
  int i0 = bi * BMt;
  int j0 = bj * BNt;
  int tid = threadIdx.x;
  int tx = tid & 15, ty = tid >> 4;

  float2 acc[TM][TN];
  #pragma unroll
  for (int r=0;r<TM;r++)
    #pragma unroll
    for (int c=0;c<TN;c++) acc[r][c] = make_float2(0.f, 0.f);

  for (int kt = 0; kt < K; kt += 16){
    for (int i = tid>>2; i < BMt; i += 64){
      int k0 = (tid & 3) * 4;
      #pragma unroll
      for (int q=0;q<4;q++)
        As[i][k0+q] = A[(long)(i0+i)*lda + kt + k0 + q];
    }
    if (TB == 0){
      for (int j = tid & 63; j < BNt; j += 64){
        #pragma unroll
        for (int r=0;r<4;r++){
          int kk = (tid >> 6) + r*4;
          Bs[kk][j] = B[(long)(kt+kk)*ldb + j0 + j];
        }
      }
    } else {
      for (int j = tid>>2; j < BNt; j += 64){
        int k0 = (tid & 3) * 4;
        #pragma unroll
        for (int q=0;q<4;q++)
          Bs[k0+q][j] = B[(long)(j0+j)*ldb + kt + k0 + q];
      }
    }
    __syncthreads();

    #pragma unroll
    for (int kk=0;kk<16;kk++){
      float2 a[TM], bv[TN];
      #pragma unroll
      for (int r=0;r<TM;r++) a[r] = As[ty + r*16][kk];
      #pragma unroll
      for (int c=0;c<TN;c++) bv[c] = Bs[kk][tx + c*16];
      #pragma unroll
      for (int r=0;r<TM;r++)
        #pragma unroll
        for (int c=0;c<TN;c++){
          acc[r][c].x = fmaf(a[r].x, bv[c].x, fmaf(-a[r].y, bv[c].y, acc[r][c].x));
          acc[r][c].y = fmaf(a[r].x, bv[c].y, fmaf( a[r].y, bv[c].x, acc[r][c].y));
        }
    }
    __syncthreads();
  }

  #pragma unroll
  for (int r=0;r<TM;r++)
    #pragma unroll
    for (int c=0;c<TN;c++){
      int i = i0 + ty + r*16;
      int j = j0 + tx + c*16;
      C[(long)i*ldc + j] = acc[r][c];
    }
}

// ---------- GEMM4: 32x32 tile, all NC slices per block, bf16 interleaved out ----------
// Xos_bf[(kx*640+ky)*NC + s] = pkbf( sum_k U[s][kx][k] * W2[ky][k] )
// Grid 20*20 = 400 blocks (XCD-swizzled).
template<int NC>
__global__ __launch_bounds__(256)
void cgemm4(const float2* __restrict__ U,   // [NC][640][320]
            const float2* __restrict__ W2,  // [640][320]
            unsigned* __restrict__ Xos)
{
  __shared__ float2 As[NC][32][17];
  __shared__ float2 Bs[16][33];

  int nwg = gridDim.x, orig = blockIdx.x;
  int qn = nwg>>3, rn = nwg&7;
  int xcd = orig&7, pos = orig>>3;
  int wg = (xcd<rn ? xcd*(qn+1) : rn*(qn+1)+(xcd-rn)*qn) + pos;
  int bj = wg % 20, bi = wg / 20;
  int i0 = bi*32, j0 = bj*32;
  int tid = threadIdx.x, tx = tid&15, ty = tid>>4;

  float2 acc[NC][2][2];
  #pragma unroll
  for (int s=0;s<NC;s++)
    #pragma unroll
    for (int r=0;r<2;r++)
      #pragma unroll
      for (int c=0;c<2;c++) acc[s][r][c] = make_float2(0.f,0.f);

  for (int kt = 0; kt < 320; kt += 16){
    { // A: NC x 32 x 16
      int i = tid>>3, k0 = (tid&7)*2;
      #pragma unroll
      for (int s=0;s<NC;s++){
        As[s][i][k0  ] = U[(long)s*204800 + (long)(i0+i)*320 + kt + k0];
        As[s][i][k0+1] = U[(long)s*204800 + (long)(i0+i)*320 + kt + k0 + 1];
      }
    }
    { // B (NT): Bs[k][j] = W2[(j0+j)*320 + kt+k]
      int j = tid>>3, k0 = (tid&7)*2;
      Bs[k0  ][j] = W2[(long)(j0+j)*320 + kt + k0];
      Bs[k0+1][j] = W2[(long)(j0+j)*320 + kt + k0 + 1];
    }
    __syncthreads();

    #pragma unroll
    for (int kk=0;kk<16;kk++){
      float2 b0 = Bs[kk][tx], b1 = Bs[kk][tx+16];
      #pragma unroll
      for (int s=0;s<NC;s++){
        float2 a0 = As[s][ty][kk], a1 = As[s][ty+16][kk];
        acc[s][0][0].x = fmaf(a0.x,b0.x, fmaf(-a0.y,b0.y, acc[s][0][0].x));
        acc[s][0][0].y = fmaf(a0.x,b0.y, fmaf( a0.y,b0.x, acc[s][0][0].y));
        acc[s][0][1].x = fmaf(a0.x,b1.x, fmaf(-a0.y,b1.y, acc[s][0][1].x));
        acc[s][0][1].y = fmaf(a0.x,b1.y, fmaf( a0.y,b1.x, acc[s][0][1].y));
        acc[s][1][0].x = fmaf(a1.x,b0.x, fmaf(-a1.y,b0.y, acc[s][1][0].x));
        acc[s][1][0].y = fmaf(a1.x,b0.y, fmaf( a1.y,b0.x, acc[s][1][0].y));
        acc[s][1][1].x = fmaf(a1.x,b1.x, fmaf(-a1.y,b1.y, acc[s][1][1].x));
        acc[s][1][1].y = fmaf(a1.x,b1.y, fmaf( a1.y,b1.x, acc[s][1][1].y));
      }
    }
    __syncthreads();
  }

  #pragma unroll
  for (int r=0;r<2;r++)
    #pragma unroll
    for (int c=0;c<2;c++){
      int i = i0 + ty + r*16;
      int j = j0 + tx + c*16;
      unsigned* dst = Xos + ((long)i*GG + j)*NC;
      unsigned w[NC];
      #pragma unroll
      for (int s=0;s<NC;s++) w[s] = pkbf(acc[s][r][c]);
      if (NC == 8){
        ((uint4*)dst)[0] = make_uint4(w[0],w[1],w[2],w[3]);
        ((uint4*)dst)[1] = make_uint4(w[4],w[5],w[6],w[7]);
      } else if (NC == 4){
        *(uint4*)dst = make_uint4(w[0],w[1],w[2],w[3]);
      } else if (NC == 2){
        *(uint2*)dst = make_uint2(w[0],w[1]);
      } else {
        dst[0] = w[0];
      }
    }
}

// ---------- per-slice mean/std, stage 1 ----------
__global__ void stats_part(const float2* __restrict__ img, double* __restrict__ part){
  int slice = blockIdx.y, seg = blockIdx.x;   // 8 x 32
  const float2* p = img + (long)slice*(HH*HH) + (long)seg*3200;
  double sr=0.0, si=0.0, srr=0.0, sii=0.0;
  for (int i = threadIdx.x; i < 3200; i += 256){
    float2 v = p[i];
    sr += (double)v.x; si += (double)v.y;
    srr += (double)v.x*(double)v.x; sii += (double)v.y*(double)v.y;
  }
  __shared__ double sh[256];
  double vals[4] = {sr, si, srr, sii};
  #pragma unroll
  for (int q=0;q<4;q++){
    sh[threadIdx.x] = vals[q];
    __syncthreads();
    for (int s=128; s>0; s>>=1){
      if (threadIdx.x < s) sh[threadIdx.x] += sh[threadIdx.x + s];
      __syncthreads();
    }
    if (threadIdx.x == 0) part[((long)slice*32 + seg)*4 + q] = sh[0];
    __syncthreads();
  }
}

// ---------- stage 2: finish (ddof=1) ----------
__global__ void stats_fin(const double* __restrict__ part, float4* __restrict__ stats){
  int b = blockIdx.x;
  int t = threadIdx.x;  // 64
  __shared__ double sh[64];
  double red[4];
  #pragma unroll
  for (int q=0;q<4;q++){
    sh[t] = (t < 32) ? part[((long)b*32 + t)*4 + q] : 0.0;
    __syncthreads();
    for (int s=32; s>0; s>>=1){
      if (t < s) sh[t] += sh[t + s];
      __syncthreads();
    }
    red[q] = sh[0];
    __syncthreads();
  }
  if (t == 0){
    double N = (double)(HH*HH);
    double mr = red[0]/N, mi = red[1]/N;
    double vr = (red[2] - N*mr*mr)/(N-1.0);
    double vi = (red[3] - N*mi*mi)/(N-1.0);
    stats[b] = make_float4((float)mr, (float)mi,
                           (float)(1.0/sqrt(vr)), (float)(1.0/sqrt(vi)));
  }
}

// ---------- normalization + apodization divide (in-place) ----------
__global__ void norm_apod(const float2* img, const float4* __restrict__ stats,
                          const float* __restrict__ rap, float2* xn){
  int idx = blockIdx.x*256 + threadIdx.x;  // 8*320*320
  if (idx >= NB*HH*HH) return;
  int b = idx / (HH*HH), rem = idx - b*(HH*HH);
  int i = rem / HH, j = rem - i*HH;
  float4 st = stats[b];
  float2 v = img[idx];
  float sc = rap[i]*rap[j];
  xn[idx] = make_float2((v.x - st.x)*st.z*sc, (v.y - st.y)*st.w*sc);
}

// ---------- KB gather, row-split, bf16 interleaved Xos [kx][ky][s] ----------
// Block = 384 threads = 6 waves x 64 points; wave w = KB row jx=w.
template<int NC>
__global__ __launch_bounds__(384)
void interp6(const float* __restrict__ tkx, const float* __restrict__ tky,
             const unsigned* __restrict__ Xos, float* __restrict__ out,
             int slice0, int cplx, float beta, float inv_i0b){
  __shared__ float2 sh[NC][6][64];
  int tid = threadIdx.x;
  int ptl = tid & 63;
  int jx  = tid >> 6;
  int p   = blockIdx.x*64 + ptl;   // 8000 blocks * 64 = 512000 exactly

  float gx = tkx[p]*2.0f, gy = tky[p]*2.0f;
  int ix0 = (int)floorf(gx) - 2;
  int iy0 = (int)floorf(gy) - 2;

  int ixu = ix0 + jx;
  int ixm = (ixu < 0) ? ixu + GG : ((ixu >= GG) ? ixu - GG : ixu);
  float wxj = kbw(gx - (float)ixu, beta, inv_i0b);

  float wy[6]; int iym[6];
  #pragma unroll
  for (int j=0;j<6;j++){
    int iyu = iy0 + j;
    wy[j] = kbw(gy - (float)iyu, beta, inv_i0b);
    iym[j] = (iyu < 0) ? iyu + GG : ((iyu >= GG) ? iyu - GG : iyu);
  }

  float2 acc[NC];
  #pragma unroll
  for (int s=0;s<NC;s++) acc[s] = make_float2(0.f, 0.f);

  const unsigned* rowp = Xos + (long)ixm*(GG*NC);
  #pragma unroll
  for (int jy=0;jy<6;jy++){
    float w = wy[jy];
    const unsigned* s2 = rowp + iym[jy]*NC;
    unsigned uu[NC];
    if (NC == 8){
      uint4 v0 = ((const uint4*)s2)[0], v1 = ((const uint4*)s2)[1];
      uu[0]=v0.x; uu[1]=v0.y; uu[2]=v0.z; uu[3]=v0.w;
      uu[4]=v1.x; uu[5]=v1.y; uu[6]=v1.z; uu[7]=v1.w;
    } else if (NC == 4){
      uint4 v = *(const uint4*)s2;
      uu[0]=v.x; uu[1]=v.y; uu[2]=v.z; uu[3]=v.w;
    } else if (NC == 2){
      uint2 v = *(const uint2*)s2;
      uu[0]=v.x; uu[1]=v.y;
    } else {
      uu[0] = s2[0];
    }
    #pragma unroll
    for (int s=0;s<NC;s++){
      float re = __uint_as_float(uu[s] << 16);
      float im = __uint_as_float(uu[s] & 0xffff0000u);
      acc[s].x = fmaf(w, re, acc[s].x);
      acc[s].y = fmaf(w, im, acc[s].y);
    }
  }
  #pragma unroll
  for (int s=0;s<NC;s++)
    sh[s][jx][ptl] = make_float2(acc[s].x*wxj, acc[s].y*wxj);
  __syncthreads();

  // reduce: pt-fastest indexing (consecutive lanes -> consecutive addresses)
  for (int t2 = tid; t2 < 64*NC; t2 += 384){
    int pt = t2 & 63;
    int s  = t2 >> 6;
    float2 r = make_float2(0.f, 0.f);
    #pragma unroll
    for (int j=0;j<6;j++){
      float2 v = sh[s][j][pt];
      r.x += v.x; r.y += v.y;
    }
    long pg = (long)blockIdx.x*64 + pt;
    if (cplx){
      ((float2*)out)[(long)(slice0+s)*PTS + pg] = r;
    } else {
      out[(long)(slice0+s)*PTS + pg] = r.x;
    }
  }
}

// ---------- launch ----------
extern "C" void kernel_launch(void* const* d_in, const int* in_sizes, int n_in,
                              void* d_out, int out_size, void* d_ws, size_t ws_size,
                              hipStream_t stream) {
  const float* kr  = (const float*)d_in[0];
  const float* ki  = (const float*)d_in[1];
  const float* tkx = (const float*)d_in[2];
  const float* tky = (const float*)d_in[3];
  char* ws = (char*)d_ws;

  // ---- fixed workspace layout ----
  float2* M1    = (float2*)(ws + 0);          //   819,200 B
  float2* W2    = (float2*)(ws + 819200);     // 1,638,400 B -> 2,457,600
  float*  rap   = (float*) (ws + 2457600);    //     1,280 B -> 2,458,880
  float4* stats = (float4*)(ws + 2458880);    //       128 B -> 2,459,008
  double* part  = (double*)(ws + 2459008);    //     8,192 B -> 2,467,200
  float2* P     = (float2*)(ws + 2467200);    // 6,553,600 B -> 9,020,800  (Kc -> image -> xn)
  const long base = 9020800;                  // Q/U/Xos region beyond

  // per-slice beyond base: U (f32, 1,638,400 B) + Xos bf16 (640*640*4 B = 1,638,400 B)
  int nc = 1;
  if      (ws_size >= (size_t)(base + 8L*3276800)) nc = 8;   // 35,235,200
  else if (ws_size >= (size_t)(base + 4L*3276800)) nc = 4;   // 22,128,000
  else if (ws_size >= (size_t)(base + 2L*3276800)) nc = 2;   // 15,574,400
  if (ws_size < (size_t)(base + 6553600)) return;            // need Q region too (15.57 MB proven)

  float2*   Q   = (float2*)(ws + base);                      // GEMM1/2 temp (6.55 MB)
  float2*   U   = (float2*)(ws + base);                      // nc * 1,638,400 B
  unsigned* Xos = (unsigned*)(ws + base + (long)nc*1638400); // nc * 1,638,400 B (bf16, interleaved)

  int cplx = (out_size >= 8192000) ? 1 : 0;

  // host-side constants
  double beta_d = M_PI * sqrt(9.0*2.25 - 0.8);
  double qq = beta_d*beta_d/4.0, term = 1.0, i0b = 1.0;
  for (int k=1;k<64;k++){ term *= qq/((double)k*(double)k); i0b += term; }
  float beta = (float)beta_d;
  float inv_i0b = (float)(1.0/i0b);

  build_m1 <<<400, 256, 0, stream>>>(M1);
  build_w2 <<<800, 256, 0, stream>>>(W2);
  build_rap<<<1,   320, 0, stream>>>(rap, beta);
  pack_c   <<<3200,256, 0, stream>>>(kr, ki, P, NB*HH*HH);

  // Q[b] = Kc[b] * M1^T   (tile 32x64: gx=5, gy=10, gz=8 -> 400 blocks)
  cgemm<1,2,4><<<400, 256, 0, stream>>>(P,320,102400, M1,320,0,
                                        Q,320,102400, 320, 5,10);
  // P[b] = M1 * Q[b]
  cgemm<0,2,4><<<400, 256, 0, stream>>>(M1,320,0, Q,320,102400,
                                        P,320,102400, 320, 5,10);
  stats_part<<<dim3(32,NB), 256, 0, stream>>>(P, part);
  stats_fin <<<NB, 64, 0, stream>>>(part, stats);
  norm_apod <<<3200, 256, 0, stream>>>(P, stats, rap, P);   // in-place

  for (int c = 0; c < NB/nc; ++c){
    // U[s] = W2 (640x320) * xn[c*nc+s]   (tile 32x64: gx=5, gy=20, gz=nc)
    cgemm<0,2,4><<<100*nc, 256, 0, stream>>>(W2,320,0, P + (long)c*nc*102400,320,102400,
                                             U,320,204800, 320, 5,20);
    // Xos bf16 interleaved, all nc slices per block (grid 400)
    switch (nc){
      case 8: cgemm4<8><<<400,256,0,stream>>>(U, W2, Xos);
              interp6<8><<<8000,384,0,stream>>>(tkx,tky,Xos,(float*)d_out, c*8, cplx, beta, inv_i0b); break;
      case 4: cgemm4<4><<<400,256,0,stream>>>(U, W2, Xos);
              interp6<4><<<8000,384,0,stream>>>(tkx,tky,Xos,(float*)d_out, c*4, cplx, beta, inv_i0b); break;
      case 2: cgemm4<2><<<400,256,0,stream>>>(U, W2, Xos);
              interp6<2><<<8000,384,0,stream>>>(tkx,tky,Xos,(float*)d_out, c*2, cplx, beta, inv_i0b); break;
      default: cgemm4<1><<<400,256,0,stream>>>(U, W2, Xos);
              interp6<1><<<8000,384,0,stream>>>(tkx,tky,Xos,(float*)d_out, c,   cplx, beta, inv_i0b); break;
    }
  }
}

// Round 11
// 418.732 us; speedup vs baseline: 1.4591x; 1.1607x over previous
//
#include <hip/hip_runtime.h>
#include <math.h>

#ifndef M_PI
#define M_PI 3.14159265358979323846
#endif

// ---------- constants ----------
#define HH   320
#define GG   640
#define NB   8
#define PTS  512000   // 800 * 640

typedef __attribute__((ext_vector_type(8))) short short8_t;
typedef __attribute__((ext_vector_type(4))) float f32x4;

// ---------- helpers ----------
__device__ __forceinline__ float bessel_i0f(float x){
  if (x < 3.75f){
    float t = (x*x) * (1.0f/(3.75f*3.75f));
    return 1.0f + t*(3.5156229f + t*(3.0899424f + t*(1.2067492f +
                 t*(0.2659732f + t*(0.0360768f + t*0.0045813f)))));
  } else {
    float t = 3.75f/x;
    float p = 0.39894228f + t*(0.01328592f + t*(0.00225319f + t*(-0.00157565f +
              t*(0.00916281f + t*(-0.02057706f + t*(0.02635537f +
              t*(-0.01647633f + t*0.00392377f)))))));
    return expf(x)*rsqrtf(x)*p;
  }
}

__device__ __forceinline__ float kbw(float d, float beta, float inv_i0b){
  float q = d * 0.33333333333333f;        // 2d/W with W=6
  float u = 1.0f - q*q;
  u = fmaxf(u, 0.0f);
  return bessel_i0f(beta * sqrtf(u)) * inv_i0b;
}

// f32 -> bf16 (RNE)
__device__ __forceinline__ short bfr(float x){
  unsigned u = __float_as_uint(x);
  u = (u + 0x7fffu + ((u>>16)&1u)) >> 16;
  return (short)u;
}
// pack float2 -> complex bf16 (re low16, im high16), RNE
__device__ __forceinline__ unsigned pkbf(float2 v){
  unsigned a = __float_as_uint(v.x);
  a = (a + 0x7fffu + ((a>>16)&1u)) >> 16;
  unsigned b = __float_as_uint(v.y);
  b = (b + 0x7fffu + ((b>>16)&1u)) & 0xffff0000u;
  return a | b;
}

// ---------- build DFT matrices ----------
__global__ void build_m1(float2* __restrict__ M1){
  int idx = blockIdx.x*256 + threadIdx.x;
  if (idx >= HH*HH) return;
  int x = idx / HH, k = idx - x*HH;
  int r = (x*k) % HH;
  float ang = (float)r * (6.283185307179586f/(float)HH);
  float s, c; sincosf(ang, &s, &c);
  float sg = ((x + k) & 1) ? -0.05590169943749474f : 0.05590169943749474f;
  M1[idx] = make_float2(sg*c, sg*s);
}

// W2[k][m] = exp(-2*pi*i*k*(m-160)/640), plus bf16 planes Wr/Wi/nWi (same layout)
__global__ void build_w2(float2* __restrict__ W2, short* __restrict__ Wr,
                         short* __restrict__ Wi, short* __restrict__ nWi){
  int idx = blockIdx.x*256 + threadIdx.x;
  if (idx >= GG*HH) return;
  int k = idx / HH, m = idx - k*HH;
  int t = (k * (m - 160)) % GG; if (t < 0) t += GG;
  float ang = (float)t * (6.283185307179586f/(float)GG);
  float s, c; sincosf(ang, &s, &c);
  W2[idx] = make_float2(c, -s);
  Wr[idx]  = bfr(c);
  Wi[idx]  = bfr(-s);
  nWi[idx] = bfr(s);
}

__global__ void build_rap(float* __restrict__ rap, float beta){
  int n = threadIdx.x;  // 320 threads
  if (n >= HH) return;
  float f = (float)(n - 160) * (1.0f/(float)GG);
  float w = 3.14159265358979f * 6.0f * f;
  float t = beta*beta - w*w;
  float z = fmaxf(sqrtf(fabsf(t)), 1e-7f);
  float a = (t > 0.0f ? sinhf(z) : sinf(z)) / z;
  float a0 = sinhf(beta) / beta;
  rap[n] = a0 / a;
}

__global__ void pack_c(const float* __restrict__ re, const float* __restrict__ im,
                       float2* __restrict__ out, int n){
  int i = blockIdx.x*256 + threadIdx.x;
  if (i < n) out[i] = make_float2(re[i], im[i]);
}

// ---------- generic complex GEMM (GEMM1/2), XCD-swizzled ----------
template<int TB, int TM, int TN>
__global__ __launch_bounds__(256)
void cgemm(const float2* __restrict__ A, int lda, long abatch,
           const float2* __restrict__ B, int ldb, long bbatch,
           float2* __restrict__ C, int ldc, long cbatch,
           int K, int gx, int gy)
{
  constexpr int BMt = 16*TM, BNt = 16*TN;
  __shared__ float2 As[BMt][17];
  __shared__ float2 Bs[16][BNt+1];

  int nwg  = gridDim.x;
  int orig = blockIdx.x;
  int qn = nwg >> 3, rn = nwg & 7;
  int xcd = orig & 7, pos = orig >> 3;
  int wg = (xcd < rn ? xcd*(qn+1) : rn*(qn+1) + (xcd-rn)*qn) + pos;
  int bj = wg % gx; int t2 = wg / gx; int bi = t2 % gy; int bz = t2 / gy;

  A += (long)bz * abatch;
  B += (long)bz * bbatch;
  C += (long)bz * cbatch;
  int i0 = bi * BMt;
  int j0 = bj * BNt;
  int tid = threadIdx.x;
  int tx = tid & 15, ty = tid >> 4;

  float2 acc[TM][TN];
  #pragma unroll
  for (int r=0;r<TM;r++)
    #pragma unroll
    for (int c=0;c<TN;c++) acc[r][c] = make_float2(0.f, 0.f);

  for (int kt = 0; kt < K; kt += 16){
    for (int i = tid>>2; i < BMt; i += 64){
      int k0 = (tid & 3) * 4;
      #pragma unroll
      for (int q=0;q<4;q++)
        As[i][k0+q] = A[(long)(i0+i)*lda + kt + k0 + q];
    }
    if (TB == 0){
      for (int j = tid & 63; j < BNt; j += 64){
        #pragma unroll
        for (int r=0;r<4;r++){
          int kk = (tid >> 6) + r*4;
          Bs[kk][j] = B[(long)(kt+kk)*ldb + j0 + j];
        }
      }
    } else {
      for (int j = tid>>2; j < BNt; j += 64){
        int k0 = (tid & 3) * 4;
        #pragma unroll
        for (int q=0;q<4;q++)
          Bs[k0+q][j] = B[(long)(j0+j)*ldb + kt + k0 + q];
      }
    }
    __syncthreads();

    #pragma unroll
    for (int kk=0;kk<16;kk++){
      float2 a[TM], bv[TN];
      #pragma unroll
      for (int r=0;r<TM;r++) a[r] = As[ty + r*16][kk];
      #pragma unroll
      for (int c=0;c<TN;c++) bv[c] = Bs[kk][tx + c*16];
      #pragma unroll
      for (int r=0;r<TM;r++)
        #pragma unroll
        for (int c=0;c<TN;c++){
          acc[r][c].x = fmaf(a[r].x, bv[c].x, fmaf(-a[r].y, bv[c].y, acc[r][c].x));
          acc[r][c].y = fmaf(a[r].x, bv[c].y, fmaf( a[r].y, bv[c].x, acc[r][c].y));
        }
    }
    __syncthreads();
  }

  #pragma unroll
  for (int r=0;r<TM;r++)
    #pragma unroll
    for (int c=0;c<TN;c++){
      int i = i0 + ty + r*16;
      int j = j0 + tx + c*16;
      C[(long)i*ldc + j] = acc[r][c];
    }
}

// ---------- GEMM3: U = W2 * xn, output as TWO bf16 planes (Ur, Ui) ----------
template<int TM, int TN>
__global__ __launch_bounds__(256)
void cgemm3bf(const float2* __restrict__ A, int lda,
              const float2* __restrict__ B, int ldb, long bbatch,
              short* __restrict__ Cr, short* __restrict__ Ci, long cbatch,
              int K, int gx, int gy)
{
  constexpr int BMt = 16*TM, BNt = 16*TN;
  __shared__ float2 As[BMt][17];
  __shared__ float2 Bs[16][BNt+1];

  int nwg  = gridDim.x;
  int orig = blockIdx.x;
  int qn = nwg >> 3, rn = nwg & 7;
  int xcd = orig & 7, pos = orig >> 3;
  int wg = (xcd < rn ? xcd*(qn+1) : rn*(qn+1) + (xcd-rn)*qn) + pos;
  int bj = wg % gx; int t2 = wg / gx; int bi = t2 % gy; int bz = t2 / gy;

  B += (long)bz * bbatch;
  int i0 = bi * BMt;
  int j0 = bj * BNt;
  int tid = threadIdx.x;
  int tx = tid & 15, ty = tid >> 4;

  float2 acc[TM][TN];
  #pragma unroll
  for (int r=0;r<TM;r++)
    #pragma unroll
    for (int c=0;c<TN;c++) acc[r][c] = make_float2(0.f, 0.f);

  for (int kt = 0; kt < K; kt += 16){
    for (int i = tid>>2; i < BMt; i += 64){
      int k0 = (tid & 3) * 4;
      #pragma unroll
      for (int q=0;q<4;q++)
        As[i][k0+q] = A[(long)(i0+i)*lda + kt + k0 + q];
    }
    for (int j = tid & 63; j < BNt; j += 64){
      #pragma unroll
      for (int r=0;r<4;r++){
        int kk = (tid >> 6) + r*4;
        Bs[kk][j] = B[(long)(kt+kk)*ldb + j0 + j];
      }
    }
    __syncthreads();

    #pragma unroll
    for (int kk=0;kk<16;kk++){
      float2 a[TM], bv[TN];
      #pragma unroll
      for (int r=0;r<TM;r++) a[r] = As[ty + r*16][kk];
      #pragma unroll
      for (int c=0;c<TN;c++) bv[c] = Bs[kk][tx + c*16];
      #pragma unroll
      for (int r=0;r<TM;r++)
        #pragma unroll
        for (int c=0;c<TN;c++){
          acc[r][c].x = fmaf(a[r].x, bv[c].x, fmaf(-a[r].y, bv[c].y, acc[r][c].x));
          acc[r][c].y = fmaf(a[r].x, bv[c].y, fmaf( a[r].y, bv[c].x, acc[r][c].y));
        }
    }
    __syncthreads();
  }

  #pragma unroll
  for (int r=0;r<TM;r++)
    #pragma unroll
    for (int c=0;c<TN;c++){
      int i = i0 + ty + r*16;
      int j = j0 + tx + c*16;
      long o = (long)bz*cbatch + (long)i*HH + j;
      Cr[o] = bfr(acc[r][c].x);
      Ci[o] = bfr(acc[r][c].y);
    }
}

// ---------- GEMM4: bf16 MFMA. Wave = one 16x16 tile of one slice ----------
// Xos[(kx*640+ky)*NC + s] = pkbf( sum_my U[s][kx][my] * W2[ky][my] )
// Block = NC waves (all slices of one tile). Grid 40*40 = 1600, XCD-swizzled.
template<int NC>
__global__ __launch_bounds__(64*NC)
void cgemm4_mfma(const short* __restrict__ Ur, const short* __restrict__ Ui,
                 const short* __restrict__ Wr, const short* __restrict__ Wi,
                 const short* __restrict__ nWi, unsigned* __restrict__ Xos)
{
  __shared__ unsigned sh[256*NC];
  int nwg = gridDim.x, orig = blockIdx.x;
  int qn = nwg>>3, rn = nwg&7;
  int xcd = orig&7, pos = orig>>3;
  int wg = (xcd<rn ? xcd*(qn+1) : rn*(qn+1)+(xcd-rn)*qn) + pos;
  int bj = wg % 40, bi = wg / 40;
  int i0 = bi*16, j0 = bj*16;
  int l = threadIdx.x & 63, wid = threadIdx.x >> 6;

  // A frag: row = l&15, k = (l>>4)*8 + j (contiguous 8 bf16 = 16B)
  long aoff = (long)wid*204800 + (long)(i0 + (l&15))*HH + ((l>>4)<<3);
  const short* par = Ur + aoff;
  const short* pai = Ui + aoff;
  // B frag: col = l&15, same k pattern; planes stored [ky][my] row-major
  long boff = (long)(j0 + (l&15))*HH + ((l>>4)<<3);
  const short* pbr = Wr  + boff;
  const short* pbi = Wi  + boff;
  const short* pbn = nWi + boff;

  f32x4 accR = {0.f,0.f,0.f,0.f}, accI = {0.f,0.f,0.f,0.f};
  #pragma unroll
  for (int kt = 0; kt < 320; kt += 32){
    short8_t aR = *(const short8_t*)(par + kt);
    short8_t aI = *(const short8_t*)(pai + kt);
    short8_t bR = *(const short8_t*)(pbr + kt);
    short8_t bI = *(const short8_t*)(pbi + kt);
    short8_t bN = *(const short8_t*)(pbn + kt);
    accR = __builtin_amdgcn_mfma_f32_16x16x32_bf16(aR, bR, accR, 0,0,0);
    accR = __builtin_amdgcn_mfma_f32_16x16x32_bf16(aI, bN, accR, 0,0,0);
    accI = __builtin_amdgcn_mfma_f32_16x16x32_bf16(aR, bI, accI, 0,0,0);
    accI = __builtin_amdgcn_mfma_f32_16x16x32_bf16(aI, bR, accI, 0,0,0);
  }

  // C/D layout: col = l&15, row = (l>>4)*4 + reg  [m89]
  int col = l & 15, r0 = (l>>4)*4;
  #pragma unroll
  for (int r=0;r<4;r++)
    sh[(r0+r)*16*NC + col*NC + wid] = pkbf(make_float2(accR[r], accI[r]));
  __syncthreads();

  // dense write: each thread one uint4; row-chunks contiguous in Xos
  int t = threadIdx.x;
  int row = t/(4*NC), q = t - row*(4*NC);
  uint4 v = ((const uint4*)(sh + row*16*NC))[q];
  ((uint4*)(Xos + ((long)(i0+row)*GG + j0)*NC))[q] = v;
}

// ---------- per-slice mean/std, stage 1 ----------
__global__ void stats_part(const float2* __restrict__ img, double* __restrict__ part){
  int slice = blockIdx.y, seg = blockIdx.x;   // 8 x 32
  const float2* p = img + (long)slice*(HH*HH) + (long)seg*3200;
  double sr=0.0, si=0.0, srr=0.0, sii=0.0;
  for (int i = threadIdx.x; i < 3200; i += 256){
    float2 v = p[i];
    sr += (double)v.x; si += (double)v.y;
    srr += (double)v.x*(double)v.x; sii += (double)v.y*(double)v.y;
  }
  __shared__ double sh[256];
  double vals[4] = {sr, si, srr, sii};
  #pragma unroll
  for (int q=0;q<4;q++){
    sh[threadIdx.x] = vals[q];
    __syncthreads();
    for (int s=128; s>0; s>>=1){
      if (threadIdx.x < s) sh[threadIdx.x] += sh[threadIdx.x + s];
      __syncthreads();
    }
    if (threadIdx.x == 0) part[((long)slice*32 + seg)*4 + q] = sh[0];
    __syncthreads();
  }
}

// ---------- stage 2: finish (ddof=1) ----------
__global__ void stats_fin(const double* __restrict__ part, float4* __restrict__ stats){
  int b = blockIdx.x;
  int t = threadIdx.x;  // 64
  __shared__ double sh[64];
  double red[4];
  #pragma unroll
  for (int q=0;q<4;q++){
    sh[t] = (t < 32) ? part[((long)b*32 + t)*4 + q] : 0.0;
    __syncthreads();
    for (int s=32; s>0; s>>=1){
      if (t < s) sh[t] += sh[t + s];
      __syncthreads();
    }
    red[q] = sh[0];
    __syncthreads();
  }
  if (t == 0){
    double N = (double)(HH*HH);
    double mr = red[0]/N, mi = red[1]/N;
    double vr = (red[2] - N*mr*mr)/(N-1.0);
    double vi = (red[3] - N*mi*mi)/(N-1.0);
    stats[b] = make_float4((float)mr, (float)mi,
                           (float)(1.0/sqrt(vr)), (float)(1.0/sqrt(vi)));
  }
}

// ---------- normalization + apodization divide (in-place) ----------
__global__ void norm_apod(const float2* img, const float4* __restrict__ stats,
                          const float* __restrict__ rap, float2* xn){
  int idx = blockIdx.x*256 + threadIdx.x;  // 8*320*320
  if (idx >= NB*HH*HH) return;
  int b = idx / (HH*HH), rem = idx - b*(HH*HH);
  int i = rem / HH, j = rem - i*HH;
  float4 st = stats[b];
  float2 v = img[idx];
  float sc = rap[i]*rap[j];
  xn[idx] = make_float2((v.x - st.x)*st.z*sc, (v.y - st.y)*st.w*sc);
}

// ---------- KB gather, row-split, bf16 interleaved Xos [kx][ky][s] ----------
template<int NC>
__global__ __launch_bounds__(384)
void interp6(const float* __restrict__ tkx, const float* __restrict__ tky,
             const unsigned* __restrict__ Xos, float* __restrict__ out,
             int slice0, int cplx, float beta, float inv_i0b){
  __shared__ float2 sh[NC][6][64];
  int tid = threadIdx.x;
  int ptl = tid & 63;
  int jx  = tid >> 6;
  int p   = blockIdx.x*64 + ptl;   // 8000 blocks * 64 = 512000 exactly

  float gx = tkx[p]*2.0f, gy = tky[p]*2.0f;
  int ix0 = (int)floorf(gx) - 2;
  int iy0 = (int)floorf(gy) - 2;

  int ixu = ix0 + jx;
  int ixm = (ixu < 0) ? ixu + GG : ((ixu >= GG) ? ixu - GG : ixu);
  float wxj = kbw(gx - (float)ixu, beta, inv_i0b);

  float wy[6]; int iym[6];
  #pragma unroll
  for (int j=0;j<6;j++){
    int iyu = iy0 + j;
    wy[j] = kbw(gy - (float)iyu, beta, inv_i0b);
    iym[j] = (iyu < 0) ? iyu + GG : ((iyu >= GG) ? iyu - GG : iyu);
  }

  float2 acc[NC];
  #pragma unroll
  for (int s=0;s<NC;s++) acc[s] = make_float2(0.f, 0.f);

  const unsigned* rowp = Xos + (long)ixm*(GG*NC);
  #pragma unroll
  for (int jy=0;jy<6;jy++){
    float w = wy[jy];
    const unsigned* s2 = rowp + iym[jy]*NC;
    unsigned uu[NC];
    if constexpr (NC == 8){
      uint4 v0 = ((const uint4*)s2)[0], v1 = ((const uint4*)s2)[1];
      uu[0]=v0.x; uu[1]=v0.y; uu[2]=v0.z; uu[3]=v0.w;
      uu[4]=v1.x; uu[5]=v1.y; uu[6]=v1.z; uu[7]=v1.w;
    } else if constexpr (NC == 4){
      uint4 v = *(const uint4*)s2;
      uu[0]=v.x; uu[1]=v.y; uu[2]=v.z; uu[3]=v.w;
    } else if constexpr (NC == 2){
      uint2 v = *(const uint2*)s2;
      uu[0]=v.x; uu[1]=v.y;
    } else {
      uu[0] = s2[0];
    }
    #pragma unroll
    for (int s=0;s<NC;s++){
      float re = __uint_as_float(uu[s] << 16);
      float im = __uint_as_float(uu[s] & 0xffff0000u);
      acc[s].x = fmaf(w, re, acc[s].x);
      acc[s].y = fmaf(w, im, acc[s].y);
    }
  }
  #pragma unroll
  for (int s=0;s<NC;s++)
    sh[s][jx][ptl] = make_float2(acc[s].x*wxj, acc[s].y*wxj);
  __syncthreads();

  for (int t2 = tid; t2 < 64*NC; t2 += 384){
    int pt = t2 & 63;
    int s  = t2 >> 6;
    float2 r = make_float2(0.f, 0.f);
    #pragma unroll
    for (int j=0;j<6;j++){
      float2 v = sh[s][j][pt];
      r.x += v.x; r.y += v.y;
    }
    long pg = (long)blockIdx.x*64 + pt;
    if (cplx){
      ((float2*)out)[(long)(slice0+s)*PTS + pg] = r;
    } else {
      out[(long)(slice0+s)*PTS + pg] = r.x;
    }
  }
}

// ---------- launch ----------
extern "C" void kernel_launch(void* const* d_in, const int* in_sizes, int n_in,
                              void* d_out, int out_size, void* d_ws, size_t ws_size,
                              hipStream_t stream) {
  const float* kr  = (const float*)d_in[0];
  const float* ki  = (const float*)d_in[1];
  const float* tkx = (const float*)d_in[2];
  const float* tky = (const float*)d_in[3];
  char* ws = (char*)d_ws;

  // ---- fixed workspace layout ----
  float2* M1    = (float2*)(ws + 0);          //   819,200 B
  float2* W2    = (float2*)(ws + 819200);     // 1,638,400 B -> 2,457,600
  float*  rap   = (float*) (ws + 2457600);    //     1,280 B -> 2,458,880
  float4* stats = (float4*)(ws + 2458880);    //       128 B -> 2,459,008
  double* part  = (double*)(ws + 2459008);    //     8,192 B -> 2,467,200
  float2* P     = (float2*)(ws + 2467200);    // 6,553,600 B -> 9,020,800  (Kc -> image -> xn)
  const long base = 9020800;

  // per-chunk regions beyond base (nc slices):
  //   Ur bf16: nc*409,600 ; Ui: nc*409,600 ; Xos bf16: nc*1,638,400 ; W planes: 1,228,800
  int nc = 1;
  if      (ws_size >= (size_t)(base + 8L*2457600 + 1228800)) nc = 8;   // 29,910,400
  else if (ws_size >= (size_t)(base + 4L*2457600 + 1228800)) nc = 4;
  else if (ws_size >= (size_t)(base + 2L*2457600 + 1228800)) nc = 2;
  if (ws_size < (size_t)(base + 6553600)) return;   // Q region floor (proven safe)

  float2* Q    = (float2*)(ws + base);                       // GEMM1/2 temp (dead after GEMM2)
  short*  Ur   = (short*)(ws + base);                        // nc*409,600 B
  short*  Ui   = (short*)(ws + base + (long)nc*409600);      // nc*409,600 B
  unsigned* Xos= (unsigned*)(ws + base + (long)nc*819200);   // nc*1,638,400 B
  short*  Wr   = (short*)(ws + base + (long)nc*2457600);     // 409,600 B
  short*  Wi   = Wr + 204800;
  short*  nWi  = Wi + 204800;

  int cplx = (out_size >= 8192000) ? 1 : 0;

  // host-side constants
  double beta_d = M_PI * sqrt(9.0*2.25 - 0.8);
  double qq = beta_d*beta_d/4.0, term = 1.0, i0b = 1.0;
  for (int k=1;k<64;k++){ term *= qq/((double)k*(double)k); i0b += term; }
  float beta = (float)beta_d;
  float inv_i0b = (float)(1.0/i0b);

  build_m1 <<<400, 256, 0, stream>>>(M1);
  build_w2 <<<800, 256, 0, stream>>>(W2, Wr, Wi, nWi);
  build_rap<<<1,   320, 0, stream>>>(rap, beta);
  pack_c   <<<3200,256, 0, stream>>>(kr, ki, P, NB*HH*HH);

  // Q[b] = Kc[b] * M1^T   (tile 32x64: gx=5, gy=10, gz=8 -> 400 blocks)
  cgemm<1,2,4><<<400, 256, 0, stream>>>(P,320,102400, M1,320,0,
                                        Q,320,102400, 320, 5,10);
  // P[b] = M1 * Q[b]
  cgemm<0,2,4><<<400, 256, 0, stream>>>(M1,320,0, Q,320,102400,
                                        P,320,102400, 320, 5,10);
  stats_part<<<dim3(32,NB), 256, 0, stream>>>(P, part);
  stats_fin <<<NB, 64, 0, stream>>>(part, stats);
  norm_apod <<<3200, 256, 0, stream>>>(P, stats, rap, P);   // in-place

  for (int c = 0; c < NB/nc; ++c){
    // U planes (bf16) = W2 (640x320) * xn[c*nc+s]   (tile 32x64: gx=5, gy=20, gz=nc)
    cgemm3bf<2,4><<<100*nc, 256, 0, stream>>>(W2,320, P + (long)c*nc*102400,320,102400,
                                              Ur, Ui, 204800, 320, 5,20);
    // Xos bf16 interleaved via MFMA, then gather
    switch (nc){
      case 8: cgemm4_mfma<8><<<1600,512,0,stream>>>(Ur,Ui,Wr,Wi,nWi,Xos);
              interp6<8><<<8000,384,0,stream>>>(tkx,tky,Xos,(float*)d_out, c*8, cplx, beta, inv_i0b); break;
      case 4: cgemm4_mfma<4><<<1600,256,0,stream>>>(Ur,Ui,Wr,Wi,nWi,Xos);
              interp6<4><<<8000,384,0,stream>>>(tkx,tky,Xos,(float*)d_out, c*4, cplx, beta, inv_i0b); break;
      case 2: cgemm4_mfma<2><<<1600,128,0,stream>>>(Ur,Ui,Wr,Wi,nWi,Xos);
              interp6<2><<<8000,384,0,stream>>>(tkx,tky,Xos,(float*)d_out, c*2, cplx, beta, inv_i0b); break;
      default: cgemm4_mfma<1><<<1600,64,0,stream>>>(Ur,Ui,Wr,Wi,nWi,Xos);
              interp6<1><<<8000,384,0,stream>>>(tkx,tky,Xos,(float*)d_out, c,   cplx, beta, inv_i0b); break;
    }
  }
}

// Round 12
// 356.933 us; speedup vs baseline: 1.7118x; 1.1731x over previous
//
#include <hip/hip_runtime.h>
#include <math.h>

#ifndef M_PI
#define M_PI 3.14159265358979323846
#endif

// ---------- constants ----------
#define HH   320
#define GG   640
#define NB   8
#define PTS  512000   // 800 * 640

typedef __attribute__((ext_vector_type(8))) short short8_t;
typedef __attribute__((ext_vector_type(4))) float f32x4;

// ---------- helpers ----------
__device__ __forceinline__ float bessel_i0f(float x){
  if (x < 3.75f){
    float t = (x*x) * (1.0f/(3.75f*3.75f));
    return 1.0f + t*(3.5156229f + t*(3.0899424f + t*(1.2067492f +
                 t*(0.2659732f + t*(0.0360768f + t*0.0045813f)))));
  } else {
    float t = 3.75f/x;
    float p = 0.39894228f + t*(0.01328592f + t*(0.00225319f + t*(-0.00157565f +
              t*(0.00916281f + t*(-0.02057706f + t*(0.02635537f +
              t*(-0.01647633f + t*0.00392377f)))))));
    return expf(x)*rsqrtf(x)*p;
  }
}

__device__ __forceinline__ float kbw(float d, float beta, float inv_i0b){
  float q = d * 0.33333333333333f;        // 2d/W with W=6
  float u = 1.0f - q*q;
  u = fmaxf(u, 0.0f);
  return bessel_i0f(beta * sqrtf(u)) * inv_i0b;
}

// f32 -> bf16 (RNE)
__device__ __forceinline__ short bfr(float x){
  unsigned u = __float_as_uint(x);
  u = (u + 0x7fffu + ((u>>16)&1u)) >> 16;
  return (short)u;
}
// pack float2 -> complex bf16 (re low16, im high16), RNE
__device__ __forceinline__ unsigned pkbf(float2 v){
  unsigned a = __float_as_uint(v.x);
  a = (a + 0x7fffu + ((a>>16)&1u)) >> 16;
  unsigned b = __float_as_uint(v.y);
  b = (b + 0x7fffu + ((b>>16)&1u)) & 0xffff0000u;
  return a | b;
}

// ---------- build DFT matrices ----------
__global__ void build_m1(float2* __restrict__ M1){
  int idx = blockIdx.x*256 + threadIdx.x;
  if (idx >= HH*HH) return;
  int x = idx / HH, k = idx - x*HH;
  int r = (x*k) % HH;
  float ang = (float)r * (6.283185307179586f/(float)HH);
  float s, c; sincosf(ang, &s, &c);
  float sg = ((x + k) & 1) ? -0.05590169943749474f : 0.05590169943749474f;
  M1[idx] = make_float2(sg*c, sg*s);
}

// W2 bf16 planes only: Wr[k][m]=cos, Wi[k][m]=-sin  (W2 = exp(-2pi i k (m-160)/640))
__global__ void build_w2(short* __restrict__ Wr, short* __restrict__ Wi){
  int idx = blockIdx.x*256 + threadIdx.x;
  if (idx >= GG*HH) return;
  int k = idx / HH, m = idx - k*HH;
  int t = (k * (m - 160)) % GG; if (t < 0) t += GG;
  float ang = (float)t * (6.283185307179586f/(float)GG);
  float s, c; sincosf(ang, &s, &c);
  Wr[idx] = bfr(c);
  Wi[idx] = bfr(-s);
}

__global__ void build_rap(float* __restrict__ rap, float beta){
  int n = threadIdx.x;  // 320 threads
  if (n >= HH) return;
  float f = (float)(n - 160) * (1.0f/(float)GG);
  float w = 3.14159265358979f * 6.0f * f;
  float t = beta*beta - w*w;
  float z = fmaxf(sqrtf(fabsf(t)), 1e-7f);
  float a = (t > 0.0f ? sinhf(z) : sinf(z)) / z;
  float a0 = sinhf(beta) / beta;
  rap[n] = a0 / a;
}

__global__ void pack_c(const float* __restrict__ re, const float* __restrict__ im,
                       float2* __restrict__ out, int n){
  int i = blockIdx.x*256 + threadIdx.x;
  if (i < n) out[i] = make_float2(re[i], im[i]);
}

// ---------- generic complex GEMM (GEMM1/2), XCD-swizzled ----------
template<int TB, int TM, int TN>
__global__ __launch_bounds__(256)
void cgemm(const float2* __restrict__ A, int lda, long abatch,
           const float2* __restrict__ B, int ldb, long bbatch,
           float2* __restrict__ C, int ldc, long cbatch,
           int K, int gx, int gy)
{
  constexpr int BMt = 16*TM, BNt = 16*TN;
  __shared__ float2 As[BMt][17];
  __shared__ float2 Bs[16][BNt+1];

  int nwg  = gridDim.x;
  int orig = blockIdx.x;
  int qn = nwg >> 3, rn = nwg & 7;
  int xcd = orig & 7, pos = orig >> 3;
  int wg = (xcd < rn ? xcd*(qn+1) : rn*(qn+1) + (xcd-rn)*qn) + pos;
  int bj = wg % gx; int t2 = wg / gx; int bi = t2 % gy; int bz = t2 / gy;

  A += (long)bz * abatch;
  B += (long)bz * bbatch;
  C += (long)bz * cbatch;
  int i0 = bi * BMt;
  int j0 = bj * BNt;
  int tid = threadIdx.x;
  int tx = tid & 15, ty = tid >> 4;

  float2 acc[TM][TN];
  #pragma unroll
  for (int r=0;r<TM;r++)
    #pragma unroll
    for (int c=0;c<TN;c++) acc[r][c] = make_float2(0.f, 0.f);

  for (int kt = 0; kt < K; kt += 16){
    for (int i = tid>>2; i < BMt; i += 64){
      int k0 = (tid & 3) * 4;
      #pragma unroll
      for (int q=0;q<4;q++)
        As[i][k0+q] = A[(long)(i0+i)*lda + kt + k0 + q];
    }
    if (TB == 0){
      for (int j = tid & 63; j < BNt; j += 64){
        #pragma unroll
        for (int r=0;r<4;r++){
          int kk = (tid >> 6) + r*4;
          Bs[kk][j] = B[(long)(kt+kk)*ldb + j0 + j];
        }
      }
    } else {
      for (int j = tid>>2; j < BNt; j += 64){
        int k0 = (tid & 3) * 4;
        #pragma unroll
        for (int q=0;q<4;q++)
          Bs[k0+q][j] = B[(long)(j0+j)*ldb + kt + k0 + q];
      }
    }
    __syncthreads();

    #pragma unroll
    for (int kk=0;kk<16;kk++){
      float2 a[TM], bv[TN];
      #pragma unroll
      for (int r=0;r<TM;r++) a[r] = As[ty + r*16][kk];
      #pragma unroll
      for (int c=0;c<TN;c++) bv[c] = Bs[kk][tx + c*16];
      #pragma unroll
      for (int r=0;r<TM;r++)
        #pragma unroll
        for (int c=0;c<TN;c++){
          acc[r][c].x = fmaf(a[r].x, bv[c].x, fmaf(-a[r].y, bv[c].y, acc[r][c].x));
          acc[r][c].y = fmaf(a[r].x, bv[c].y, fmaf( a[r].y, bv[c].x, acc[r][c].y));
        }
    }
    __syncthreads();
  }

  #pragma unroll
  for (int r=0;r<TM;r++)
    #pragma unroll
    for (int c=0;c<TN;c++){
      int i = i0 + ty + r*16;
      int j = j0 + tx + c*16;
      C[(long)i*ldc + j] = acc[r][c];
    }
}

// ---------- per-slice mean/std, stage 1 ----------
__global__ void stats_part(const float2* __restrict__ img, double* __restrict__ part){
  int slice = blockIdx.y, seg = blockIdx.x;   // 8 x 32
  const float2* p = img + (long)slice*(HH*HH) + (long)seg*3200;
  double sr=0.0, si=0.0, srr=0.0, sii=0.0;
  for (int i = threadIdx.x; i < 3200; i += 256){
    float2 v = p[i];
    sr += (double)v.x; si += (double)v.y;
    srr += (double)v.x*(double)v.x; sii += (double)v.y*(double)v.y;
  }
  __shared__ double sh[256];
  double vals[4] = {sr, si, srr, sii};
  #pragma unroll
  for (int q=0;q<4;q++){
    sh[threadIdx.x] = vals[q];
    __syncthreads();
    for (int s=128; s>0; s>>=1){
      if (threadIdx.x < s) sh[threadIdx.x] += sh[threadIdx.x + s];
      __syncthreads();
    }
    if (threadIdx.x == 0) part[((long)slice*32 + seg)*4 + q] = sh[0];
    __syncthreads();
  }
}

// ---------- stage 2: finish (ddof=1) ----------
__global__ void stats_fin(const double* __restrict__ part, float4* __restrict__ stats){
  int b = blockIdx.x;
  int t = threadIdx.x;  // 64
  __shared__ double sh[64];
  double red[4];
  #pragma unroll
  for (int q=0;q<4;q++){
    sh[t] = (t < 32) ? part[((long)b*32 + t)*4 + q] : 0.0;
    __syncthreads();
    for (int s=32; s>0; s>>=1){
      if (t < s) sh[t] += sh[t + s];
      __syncthreads();
    }
    red[q] = sh[0];
    __syncthreads();
  }
  if (t == 0){
    double N = (double)(HH*HH);
    double mr = red[0]/N, mi = red[1]/N;
    double vr = (red[2] - N*mr*mr)/(N-1.0);
    double vi = (red[3] - N*mi*mi)/(N-1.0);
    stats[b] = make_float4((float)mr, (float)mi,
                           (float)(1.0/sqrt(vr)), (float)(1.0/sqrt(vi)));
  }
}

// ---------- normalize + apod + TRANSPOSE -> bf16 planes xnT[j][i] ----------
__global__ __launch_bounds__(256)
void tnorm(const float2* __restrict__ img, const float4* __restrict__ stats,
           const float* __restrict__ rap,
           short* __restrict__ xnTr, short* __restrict__ xnTi){
  __shared__ float2 tile[32][33];
  int b = blockIdx.z;
  int i0 = blockIdx.y*32, j0 = blockIdx.x*32;
  int tx = threadIdx.x & 31, ty = threadIdx.x >> 5;  // 32 x 8
  float4 st = stats[b];
  #pragma unroll
  for (int r=0;r<4;r++){
    int i = i0 + ty + r*8, j = j0 + tx;
    float2 v = img[(long)b*102400 + (long)i*HH + j];
    float sc = rap[i]*rap[j];
    tile[ty+r*8][tx] = make_float2((v.x-st.x)*st.z*sc, (v.y-st.y)*st.w*sc);
  }
  __syncthreads();
  #pragma unroll
  for (int r=0;r<4;r++){
    int j = j0 + ty + r*8, i = i0 + tx;
    float2 v = tile[tx][ty+r*8];
    long o = (long)b*102400 + (long)j*HH + i;
    xnTr[o] = bfr(v.x);
    xnTi[o] = bfr(v.y);
  }
}

// ---------- GEMM3 (MFMA): U[s][kx][j] = sum_m W2[kx][m] * xn[s][m][j] ----------
// A = W2 planes (shared by all waves); B = xnT planes [j][m] (contiguous in m).
// Wave = one 16x16 U-tile of one slice; block = NC waves. Grid 40*20 = 800.
template<int NC>
__global__ __launch_bounds__(64*NC)
void cgemm3_mfma(const short* __restrict__ Wr, const short* __restrict__ Wi,
                 const short* __restrict__ xnTr, const short* __restrict__ xnTi,
                 short* __restrict__ Ur, short* __restrict__ Ui, int slice0)
{
  int nwg = gridDim.x, orig = blockIdx.x;
  int qn = nwg>>3, rn = nwg&7;
  int xcd = orig&7, pos = orig>>3;
  int wg = (xcd<rn ? xcd*(qn+1) : rn*(qn+1)+(xcd-rn)*qn) + pos;
  int bj = wg % 20, bi = wg / 20;
  int i0 = bi*16, j0 = bj*16;
  int l = threadIdx.x & 63, wid = threadIdx.x >> 6;

  long aoff = (long)(i0 + (l&15))*HH + ((l>>4)<<3);
  const short* pwr = Wr + aoff;
  const short* pwi = Wi + aoff;
  long boff = (long)(slice0+wid)*102400 + (long)(j0 + (l&15))*HH + ((l>>4)<<3);
  const short* pxr = xnTr + boff;
  const short* pxi = xnTi + boff;

  f32x4 accRa = {0.f,0.f,0.f,0.f}, accRb = {0.f,0.f,0.f,0.f}, accI = {0.f,0.f,0.f,0.f};
  #pragma unroll
  for (int kt = 0; kt < 320; kt += 32){
    short8_t wR = *(const short8_t*)(pwr + kt);
    short8_t wI = *(const short8_t*)(pwi + kt);
    short8_t xR = *(const short8_t*)(pxr + kt);
    short8_t xI = *(const short8_t*)(pxi + kt);
    accRa = __builtin_amdgcn_mfma_f32_16x16x32_bf16(wR, xR, accRa, 0,0,0);
    accRb = __builtin_amdgcn_mfma_f32_16x16x32_bf16(wI, xI, accRb, 0,0,0);
    accI  = __builtin_amdgcn_mfma_f32_16x16x32_bf16(wR, xI, accI, 0,0,0);
    accI  = __builtin_amdgcn_mfma_f32_16x16x32_bf16(wI, xR, accI, 0,0,0);
  }
  int col = l & 15, r0 = (l>>4)*4;
  #pragma unroll
  for (int r=0;r<4;r++){
    long o = (long)wid*204800 + (long)(i0+r0+r)*HH + j0+col;
    Ur[o] = bfr(accRa[r] - accRb[r]);
    Ui[o] = bfr(accI[r]);
  }
}

// ---------- GEMM4 (MFMA): Xos[(kx*640+ky)*NC+s] = U[s]·W2^T, bf16 out ----------
template<int NC>
__global__ __launch_bounds__(64*NC)
void cgemm4_mfma(const short* __restrict__ Ur, const short* __restrict__ Ui,
                 const short* __restrict__ Wr, const short* __restrict__ Wi,
                 unsigned* __restrict__ Xos)
{
  __shared__ unsigned sh[256*NC];
  int nwg = gridDim.x, orig = blockIdx.x;
  int qn = nwg>>3, rn = nwg&7;
  int xcd = orig&7, pos = orig>>3;
  int wg = (xcd<rn ? xcd*(qn+1) : rn*(qn+1)+(xcd-rn)*qn) + pos;
  int bj = wg % 40, bi = wg / 40;
  int i0 = bi*16, j0 = bj*16;
  int l = threadIdx.x & 63, wid = threadIdx.x >> 6;

  long aoff = (long)wid*204800 + (long)(i0 + (l&15))*HH + ((l>>4)<<3);
  const short* par = Ur + aoff;
  const short* pai = Ui + aoff;
  long boff = (long)(j0 + (l&15))*HH + ((l>>4)<<3);
  const short* pbr = Wr + boff;
  const short* pbi = Wi + boff;

  f32x4 accRa = {0.f,0.f,0.f,0.f}, accRb = {0.f,0.f,0.f,0.f}, accI = {0.f,0.f,0.f,0.f};
  #pragma unroll
  for (int kt = 0; kt < 320; kt += 32){
    short8_t aR = *(const short8_t*)(par + kt);
    short8_t aI = *(const short8_t*)(pai + kt);
    short8_t bR = *(const short8_t*)(pbr + kt);
    short8_t bI = *(const short8_t*)(pbi + kt);
    accRa = __builtin_amdgcn_mfma_f32_16x16x32_bf16(aR, bR, accRa, 0,0,0);
    accRb = __builtin_amdgcn_mfma_f32_16x16x32_bf16(aI, bI, accRb, 0,0,0);
    accI  = __builtin_amdgcn_mfma_f32_16x16x32_bf16(aR, bI, accI, 0,0,0);
    accI  = __builtin_amdgcn_mfma_f32_16x16x32_bf16(aI, bR, accI, 0,0,0);
  }

  int col = l & 15, r0 = (l>>4)*4;
  #pragma unroll
  for (int r=0;r<4;r++)
    sh[(r0+r)*16*NC + col*NC + wid] = pkbf(make_float2(accRa[r]-accRb[r], accI[r]));
  __syncthreads();

  int t = threadIdx.x;
  int row = t/(4*NC), q = t - row*(4*NC);
  uint4 v = ((const uint4*)(sh + row*16*NC))[q];
  ((uint4*)(Xos + ((long)(i0+row)*GG + j0)*NC))[q] = v;
}

// ---------- KB gather, row-split, shared wy, bf16 interleaved Xos ----------
template<int NC>
__global__ __launch_bounds__(384)
void interp6(const float* __restrict__ tkx, const float* __restrict__ tky,
             const unsigned* __restrict__ Xos, float* __restrict__ out,
             int slice0, int cplx, float beta, float inv_i0b){
  __shared__ float2 sh[NC][6][64];
  __shared__ float swy[6][64];
  int tid = threadIdx.x;
  int ptl = tid & 63;
  int jx  = tid >> 6;
  int p   = blockIdx.x*64 + ptl;   // 8000 blocks * 64 = 512000 exactly

  float gx = tkx[p]*2.0f, gy = tky[p]*2.0f;
  int ix0 = (int)floorf(gx) - 2;
  int iy0 = (int)floorf(gy) - 2;

  int ixu = ix0 + jx;
  int ixm = (ixu < 0) ? ixu + GG : ((ixu >= GG) ? ixu - GG : ixu);
  float wxj = kbw(gx - (float)ixu, beta, inv_i0b);
  // share wy: wave jx computes only row jx's y-weight for its point
  swy[jx][ptl] = kbw(gy - (float)(iy0 + jx), beta, inv_i0b);

  int iym[6];
  #pragma unroll
  for (int j=0;j<6;j++){
    int iyu = iy0 + j;
    iym[j] = (iyu < 0) ? iyu + GG : ((iyu >= GG) ? iyu - GG : iyu);
  }
  __syncthreads();
  float wy[6];
  #pragma unroll
  for (int j=0;j<6;j++) wy[j] = swy[j][ptl];

  float2 acc[NC];
  #pragma unroll
  for (int s=0;s<NC;s++) acc[s] = make_float2(0.f, 0.f);

  const unsigned* rowp = Xos + (long)ixm*(GG*NC);
  #pragma unroll
  for (int jy=0;jy<6;jy++){
    float w = wy[jy];
    const unsigned* s2 = rowp + iym[jy]*NC;
    unsigned uu[NC];
    if constexpr (NC == 8){
      uint4 v0 = ((const uint4*)s2)[0], v1 = ((const uint4*)s2)[1];
      uu[0]=v0.x; uu[1]=v0.y; uu[2]=v0.z; uu[3]=v0.w;
      uu[4]=v1.x; uu[5]=v1.y; uu[6]=v1.z; uu[7]=v1.w;
    } else if constexpr (NC == 4){
      uint4 v = *(const uint4*)s2;
      uu[0]=v.x; uu[1]=v.y; uu[2]=v.z; uu[3]=v.w;
    } else if constexpr (NC == 2){
      uint2 v = *(const uint2*)s2;
      uu[0]=v.x; uu[1]=v.y;
    } else {
      uu[0] = s2[0];
    }
    #pragma unroll
    for (int s=0;s<NC;s++){
      float re = __uint_as_float(uu[s] << 16);
      float im = __uint_as_float(uu[s] & 0xffff0000u);
      acc[s].x = fmaf(w, re, acc[s].x);
      acc[s].y = fmaf(w, im, acc[s].y);
    }
  }
  #pragma unroll
  for (int s=0;s<NC;s++)
    sh[s][jx][ptl] = make_float2(acc[s].x*wxj, acc[s].y*wxj);
  __syncthreads();

  for (int t2 = tid; t2 < 64*NC; t2 += 384){
    int pt = t2 & 63;
    int s  = t2 >> 6;
    float2 r = make_float2(0.f, 0.f);
    #pragma unroll
    for (int j=0;j<6;j++){
      float2 v = sh[s][j][pt];
      r.x += v.x; r.y += v.y;
    }
    long pg = (long)blockIdx.x*64 + pt;
    if (cplx){
      ((float2*)out)[(long)(slice0+s)*PTS + pg] = r;
    } else {
      out[(long)(slice0+s)*PTS + pg] = r.x;
    }
  }
}

// ---------- launch ----------
extern "C" void kernel_launch(void* const* d_in, const int* in_sizes, int n_in,
                              void* d_out, int out_size, void* d_ws, size_t ws_size,
                              hipStream_t stream) {
  const float* kr  = (const float*)d_in[0];
  const float* ki  = (const float*)d_in[1];
  const float* tkx = (const float*)d_in[2];
  const float* tky = (const float*)d_in[3];
  char* ws = (char*)d_ws;

  // ---- workspace layout (bytes) ----
  float2* M1    = (float2*)(ws + 0);          //   819,200
  float*  rap   = (float*) (ws + 819200);     //     1,280 -> 820,480
  float4* stats = (float4*)(ws + 820480);     //       128 -> 820,608
  double* part  = (double*)(ws + 820608);     //     8,192 -> 828,800
  float2* P     = (float2*)(ws + 828800);     // 6,553,600 -> 7,382,400 (Kc -> image)
  float2* Q     = (float2*)(ws + 7382400);    // 6,553,600 -> 13,936,000 (GEMM1/2 temp)
  short*  xnTr  = (short*)(ws + 7382400);     // 3,276,800 (overlays Q after GEMM2)
  short*  xnTi  = (short*)(ws + 7382400 + 3276800);  // 3,276,800
  short*  Wr    = (short*)(ws + 13936000);    //   409,600 -> 14,345,600
  short*  Wi    = (short*)(ws + 14345600);    //   409,600 -> 14,755,200
  const long base = 14755200;

  // per-chunk: Ur nc*409600 | Ui nc*409600 | Xos nc*1638400  (end = base + nc*2457600)
  int nc = 1;
  if      (ws_size >= (size_t)(base + 8L*2457600)) nc = 8;   // 34,416,000 (ws>=35.2MB proven)
  else if (ws_size >= (size_t)(base + 4L*2457600)) nc = 4;
  else if (ws_size >= (size_t)(base + 2L*2457600)) nc = 2;
  if (ws_size < (size_t)(base + 2457600)) return;            // fail clean

  short*    Ur  = (short*)(ws + base);
  short*    Ui  = (short*)(ws + base + (long)nc*409600);
  unsigned* Xos = (unsigned*)(ws + base + (long)nc*819200);

  int cplx = (out_size >= 8192000) ? 1 : 0;

  // host-side constants
  double beta_d = M_PI * sqrt(9.0*2.25 - 0.8);
  double qq = beta_d*beta_d/4.0, term = 1.0, i0b = 1.0;
  for (int k=1;k<64;k++){ term *= qq/((double)k*(double)k); i0b += term; }
  float beta = (float)beta_d;
  float inv_i0b = (float)(1.0/i0b);

  build_m1 <<<400, 256, 0, stream>>>(M1);
  build_w2 <<<800, 256, 0, stream>>>(Wr, Wi);
  build_rap<<<1,   320, 0, stream>>>(rap, beta);
  pack_c   <<<3200,256, 0, stream>>>(kr, ki, P, NB*HH*HH);

  // Q[b] = Kc[b] * M1^T   (tile 32x64: gx=5, gy=10, gz=8 -> 400 blocks)
  cgemm<1,2,4><<<400, 256, 0, stream>>>(P,320,102400, M1,320,0,
                                        Q,320,102400, 320, 5,10);
  // P[b] = M1 * Q[b]
  cgemm<0,2,4><<<400, 256, 0, stream>>>(M1,320,0, Q,320,102400,
                                        P,320,102400, 320, 5,10);
  stats_part<<<dim3(32,NB), 256, 0, stream>>>(P, part);
  stats_fin <<<NB, 64, 0, stream>>>(part, stats);
  // normalize + apod + transpose -> bf16 xnT planes (Q region now dead)
  tnorm<<<dim3(10,10,NB), 256, 0, stream>>>(P, stats, rap, xnTr, xnTi);

  for (int c = 0; c < NB/nc; ++c){
    switch (nc){
      case 8:
        cgemm3_mfma<8><<<800, 512,0,stream>>>(Wr,Wi,xnTr,xnTi,Ur,Ui, c*8);
        cgemm4_mfma<8><<<1600,512,0,stream>>>(Ur,Ui,Wr,Wi,Xos);
        interp6<8><<<8000,384,0,stream>>>(tkx,tky,Xos,(float*)d_out, c*8, cplx, beta, inv_i0b);
        break;
      case 4:
        cgemm3_mfma<4><<<800, 256,0,stream>>>(Wr,Wi,xnTr,xnTi,Ur,Ui, c*4);
        cgemm4_mfma<4><<<1600,256,0,stream>>>(Ur,Ui,Wr,Wi,Xos);
        interp6<4><<<8000,384,0,stream>>>(tkx,tky,Xos,(float*)d_out, c*4, cplx, beta, inv_i0b);
        break;
      case 2:
        cgemm3_mfma<2><<<800, 128,0,stream>>>(Wr,Wi,xnTr,xnTi,Ur,Ui, c*2);
        cgemm4_mfma<2><<<1600,128,0,stream>>>(Ur,Ui,Wr,Wi,Xos);
        interp6<2><<<8000,384,0,stream>>>(tkx,tky,Xos,(float*)d_out, c*2, cplx, beta, inv_i0b);
        break;
      default:
        cgemm3_mfma<1><<<800,  64,0,stream>>>(Wr,Wi,xnTr,xnTi,Ur,Ui, c);
        cgemm4_mfma<1><<<1600, 64,0,stream>>>(Ur,Ui,Wr,Wi,Xos);
        interp6<1><<<8000,384,0,stream>>>(tkx,tky,Xos,(float*)d_out, c, cplx, beta, inv_i0b);
        break;
    }
  }
}

// Round 13
// 299.401 us; speedup vs baseline: 2.0407x; 1.1922x over previous
//
#include <hip/hip_runtime.h>
#include <math.h>

#ifndef M_PI
#define M_PI 3.14159265358979323846
#endif

// ---------- constants ----------
#define HH   320
#define GG   640
#define NB   8
#define PTS  512000   // 800 * 640

typedef __attribute__((ext_vector_type(8))) short short8_t;
typedef __attribute__((ext_vector_type(4))) float f32x4;

// ---------- helpers ----------
__device__ __forceinline__ float bessel_i0f(float x){
  if (x < 3.75f){
    float t = (x*x) * (1.0f/(3.75f*3.75f));
    return 1.0f + t*(3.5156229f + t*(3.0899424f + t*(1.2067492f +
                 t*(0.2659732f + t*(0.0360768f + t*0.0045813f)))));
  } else {
    float t = 3.75f/x;
    float p = 0.39894228f + t*(0.01328592f + t*(0.00225319f + t*(-0.00157565f +
              t*(0.00916281f + t*(-0.02057706f + t*(0.02635537f +
              t*(-0.01647633f + t*0.00392377f)))))));
    return expf(x)*rsqrtf(x)*p;
  }
}

__device__ __forceinline__ float kbw(float d, float beta, float inv_i0b){
  float q = d * 0.33333333333333f;        // 2d/W with W=6
  float u = 1.0f - q*q;
  u = fmaxf(u, 0.0f);
  return bessel_i0f(beta * sqrtf(u)) * inv_i0b;
}

// f32 -> bf16 (RNE)
__device__ __forceinline__ short bfr(float x){
  unsigned u = __float_as_uint(x);
  u = (u + 0x7fffu + ((u>>16)&1u)) >> 16;
  return (short)u;
}
// pack float2 -> complex bf16 (re low16, im high16), RNE
__device__ __forceinline__ unsigned pkbf(float2 v){
  unsigned a = __float_as_uint(v.x);
  a = (a + 0x7fffu + ((a>>16)&1u)) >> 16;
  unsigned b = __float_as_uint(v.y);
  b = (b + 0x7fffu + ((b>>16)&1u)) & 0xffff0000u;
  return a | b;
}

// ---------- builders ----------
// M1[x][k] = (1/sqrt(320)) * (-1)^(x+k) * exp(+2pi i xk/320)  (symmetric) -> bf16 planes
__global__ void build_m1bf(short* __restrict__ M1r, short* __restrict__ M1i){
  int idx = blockIdx.x*256 + threadIdx.x;
  if (idx >= HH*HH) return;
  int x = idx / HH, k = idx - x*HH;
  int r = (x*k) % HH;
  float ang = (float)r * (6.283185307179586f/(float)HH);
  float s, c; sincosf(ang, &s, &c);
  float sg = ((x + k) & 1) ? -0.05590169943749474f : 0.05590169943749474f;
  M1r[idx] = bfr(sg*c);
  M1i[idx] = bfr(sg*s);
}

// W2 bf16 planes: Wr[k][m]=cos, Wi[k][m]=-sin  (W2 = exp(-2pi i k (m-160)/640))
__global__ void build_w2(short* __restrict__ Wr, short* __restrict__ Wi){
  int idx = blockIdx.x*256 + threadIdx.x;
  if (idx >= GG*HH) return;
  int k = idx / HH, m = idx - k*HH;
  int t = (k * (m - 160)) % GG; if (t < 0) t += GG;
  float ang = (float)t * (6.283185307179586f/(float)GG);
  float s, c; sincosf(ang, &s, &c);
  Wr[idx] = bfr(c);
  Wi[idx] = bfr(-s);
}

__global__ void build_rap(float* __restrict__ rap, float beta){
  int n = threadIdx.x;  // 320 threads
  if (n >= HH) return;
  float f = (float)(n - 160) * (1.0f/(float)GG);
  float w = 3.14159265358979f * 6.0f * f;
  float t = beta*beta - w*w;
  float z = fmaxf(sqrtf(fabsf(t)), 1e-7f);
  float a = (t > 0.0f ? sinhf(z) : sinf(z)) / z;
  float a0 = sinhf(beta) / beta;
  rap[n] = a0 / a;
}

// pack input k-space into bf16 planes
__global__ void pack_bf(const float* __restrict__ re, const float* __restrict__ im,
                        short* __restrict__ Kr, short* __restrict__ Ki, int n){
  int i = blockIdx.x*256 + threadIdx.x;
  if (i < n){ Kr[i] = bfr(re[i]); Ki[i] = bfr(im[i]); }
}

// ---------- GEMM1 (MFMA): Tt[b][j][i] = sum_k M1[j][k] * Kc[b][i][k] ----------
// Wave = one 16x16 tile of one slice (wid); block = 8 waves. Grid 400 (20x20).
__global__ __launch_bounds__(512)
void gemm1_mfma(const short* __restrict__ M1r, const short* __restrict__ M1i,
                const short* __restrict__ Kr,  const short* __restrict__ Ki,
                short* __restrict__ Ttr, short* __restrict__ Tti)
{
  int nwg = gridDim.x, orig = blockIdx.x;
  int qn = nwg>>3, rn = nwg&7;
  int xcd = orig&7, pos = orig>>3;
  int wg = (xcd<rn ? xcd*(qn+1) : rn*(qn+1)+(xcd-rn)*qn) + pos;
  int ti = wg % 20, tj = wg / 20;
  int i0 = ti*16, j0 = tj*16;
  int l = threadIdx.x & 63, wid = threadIdx.x >> 6;

  long aoff = (long)(j0 + (l&15))*HH + ((l>>4)<<3);       // M1 row j
  const short* pmr = M1r + aoff;
  const short* pmi = M1i + aoff;
  long boff = (long)wid*102400 + (long)(i0 + (l&15))*HH + ((l>>4)<<3);  // Kc row i
  const short* pkr = Kr + boff;
  const short* pki = Ki + boff;

  f32x4 accRa = {0.f,0.f,0.f,0.f}, accRb = {0.f,0.f,0.f,0.f}, accI = {0.f,0.f,0.f,0.f};
  #pragma unroll
  for (int kt = 0; kt < 320; kt += 32){
    short8_t mR = *(const short8_t*)(pmr + kt);
    short8_t mI = *(const short8_t*)(pmi + kt);
    short8_t kR = *(const short8_t*)(pkr + kt);
    short8_t kI = *(const short8_t*)(pki + kt);
    accRa = __builtin_amdgcn_mfma_f32_16x16x32_bf16(mR, kR, accRa, 0,0,0);
    accRb = __builtin_amdgcn_mfma_f32_16x16x32_bf16(mI, kI, accRb, 0,0,0);
    accI  = __builtin_amdgcn_mfma_f32_16x16x32_bf16(mR, kI, accI, 0,0,0);
    accI  = __builtin_amdgcn_mfma_f32_16x16x32_bf16(mI, kR, accI, 0,0,0);
  }
  // D[row=j][col=i]: col=l&15, row=(l>>4)*4+r  -> write row-major (coalesced)
  int col = l & 15, r0 = (l>>4)*4;
  #pragma unroll
  for (int r=0;r<4;r++){
    long o = (long)wid*102400 + (long)(j0+r0+r)*HH + i0+col;
    Ttr[o] = bfr(accRa[r] - accRb[r]);
    Tti[o] = bfr(accI[r]);
  }
}

// ---------- GEMM2 (MFMA): image[b][i][j] = sum_x M1[i][x] * Tt[b][j][x] ----------
__global__ __launch_bounds__(512)
void gemm2_mfma(const short* __restrict__ M1r, const short* __restrict__ M1i,
                const short* __restrict__ Ttr, const short* __restrict__ Tti,
                float2* __restrict__ P)
{
  int nwg = gridDim.x, orig = blockIdx.x;
  int qn = nwg>>3, rn = nwg&7;
  int xcd = orig&7, pos = orig>>3;
  int wg = (xcd<rn ? xcd*(qn+1) : rn*(qn+1)+(xcd-rn)*qn) + pos;
  int tj = wg % 20, ti = wg / 20;
  int i0 = ti*16, j0 = tj*16;
  int l = threadIdx.x & 63, wid = threadIdx.x >> 6;

  long aoff = (long)(i0 + (l&15))*HH + ((l>>4)<<3);       // M1 row i
  const short* pmr = M1r + aoff;
  const short* pmi = M1i + aoff;
  long boff = (long)wid*102400 + (long)(j0 + (l&15))*HH + ((l>>4)<<3);  // Tt row j
  const short* ptr = Ttr + boff;
  const short* pti = Tti + boff;

  f32x4 accRa = {0.f,0.f,0.f,0.f}, accRb = {0.f,0.f,0.f,0.f}, accI = {0.f,0.f,0.f,0.f};
  #pragma unroll
  for (int kt = 0; kt < 320; kt += 32){
    short8_t mR = *(const short8_t*)(pmr + kt);
    short8_t mI = *(const short8_t*)(pmi + kt);
    short8_t tR = *(const short8_t*)(ptr + kt);
    short8_t tI = *(const short8_t*)(pti + kt);
    accRa = __builtin_amdgcn_mfma_f32_16x16x32_bf16(mR, tR, accRa, 0,0,0);
    accRb = __builtin_amdgcn_mfma_f32_16x16x32_bf16(mI, tI, accRb, 0,0,0);
    accI  = __builtin_amdgcn_mfma_f32_16x16x32_bf16(mR, tI, accI, 0,0,0);
    accI  = __builtin_amdgcn_mfma_f32_16x16x32_bf16(mI, tR, accI, 0,0,0);
  }
  // D[row=i][col=j] -> image float2 row-major (coalesced 128B per 16 lanes)
  int col = l & 15, r0 = (l>>4)*4;
  #pragma unroll
  for (int r=0;r<4;r++){
    long o = (long)wid*102400 + (long)(i0+r0+r)*HH + j0+col;
    P[o] = make_float2(accRa[r] - accRb[r], accI[r]);
  }
}

// ---------- per-slice mean/std, stage 1 ----------
__global__ void stats_part(const float2* __restrict__ img, double* __restrict__ part){
  int slice = blockIdx.y, seg = blockIdx.x;   // 8 x 32
  const float2* p = img + (long)slice*(HH*HH) + (long)seg*3200;
  double sr=0.0, si=0.0, srr=0.0, sii=0.0;
  for (int i = threadIdx.x; i < 3200; i += 256){
    float2 v = p[i];
    sr += (double)v.x; si += (double)v.y;
    srr += (double)v.x*(double)v.x; sii += (double)v.y*(double)v.y;
  }
  __shared__ double sh[256];
  double vals[4] = {sr, si, srr, sii};
  #pragma unroll
  for (int q=0;q<4;q++){
    sh[threadIdx.x] = vals[q];
    __syncthreads();
    for (int s=128; s>0; s>>=1){
      if (threadIdx.x < s) sh[threadIdx.x] += sh[threadIdx.x + s];
      __syncthreads();
    }
    if (threadIdx.x == 0) part[((long)slice*32 + seg)*4 + q] = sh[0];
    __syncthreads();
  }
}

// ---------- stage 2: finish (ddof=1) ----------
__global__ void stats_fin(const double* __restrict__ part, float4* __restrict__ stats){
  int b = blockIdx.x;
  int t = threadIdx.x;  // 64
  __shared__ double sh[64];
  double red[4];
  #pragma unroll
  for (int q=0;q<4;q++){
    sh[t] = (t < 32) ? part[((long)b*32 + t)*4 + q] : 0.0;
    __syncthreads();
    for (int s=32; s>0; s>>=1){
      if (t < s) sh[t] += sh[t + s];
      __syncthreads();
    }
    red[q] = sh[0];
    __syncthreads();
  }
  if (t == 0){
    double N = (double)(HH*HH);
    double mr = red[0]/N, mi = red[1]/N;
    double vr = (red[2] - N*mr*mr)/(N-1.0);
    double vi = (red[3] - N*mi*mi)/(N-1.0);
    stats[b] = make_float4((float)mr, (float)mi,
                           (float)(1.0/sqrt(vr)), (float)(1.0/sqrt(vi)));
  }
}

// ---------- normalize + apod + TRANSPOSE -> bf16 planes xnT[j][i] ----------
__global__ __launch_bounds__(256)
void tnorm(const float2* __restrict__ img, const float4* __restrict__ stats,
           const float* __restrict__ rap,
           short* __restrict__ xnTr, short* __restrict__ xnTi){
  __shared__ float2 tile[32][33];
  int b = blockIdx.z;
  int i0 = blockIdx.y*32, j0 = blockIdx.x*32;
  int tx = threadIdx.x & 31, ty = threadIdx.x >> 5;  // 32 x 8
  float4 st = stats[b];
  #pragma unroll
  for (int r=0;r<4;r++){
    int i = i0 + ty + r*8, j = j0 + tx;
    float2 v = img[(long)b*102400 + (long)i*HH + j];
    float sc = rap[i]*rap[j];
    tile[ty+r*8][tx] = make_float2((v.x-st.x)*st.z*sc, (v.y-st.y)*st.w*sc);
  }
  __syncthreads();
  #pragma unroll
  for (int r=0;r<4;r++){
    int j = j0 + ty + r*8, i = i0 + tx;
    float2 v = tile[tx][ty+r*8];
    long o = (long)b*102400 + (long)j*HH + i;
    xnTr[o] = bfr(v.x);
    xnTi[o] = bfr(v.y);
  }
}

// ---------- GEMM3 (MFMA): U[s][kx][j] = sum_m W2[kx][m] * xnT[s][j][m] ----------
template<int NC>
__global__ __launch_bounds__(64*NC)
void cgemm3_mfma(const short* __restrict__ Wr, const short* __restrict__ Wi,
                 const short* __restrict__ xnTr, const short* __restrict__ xnTi,
                 short* __restrict__ Ur, short* __restrict__ Ui, int slice0)
{
  int nwg = gridDim.x, orig = blockIdx.x;
  int qn = nwg>>3, rn = nwg&7;
  int xcd = orig&7, pos = orig>>3;
  int wg = (xcd<rn ? xcd*(qn+1) : rn*(qn+1)+(xcd-rn)*qn) + pos;
  int bj = wg % 20, bi = wg / 20;
  int i0 = bi*16, j0 = bj*16;
  int l = threadIdx.x & 63, wid = threadIdx.x >> 6;

  long aoff = (long)(i0 + (l&15))*HH + ((l>>4)<<3);
  const short* pwr = Wr + aoff;
  const short* pwi = Wi + aoff;
  long boff = (long)(slice0+wid)*102400 + (long)(j0 + (l&15))*HH + ((l>>4)<<3);
  const short* pxr = xnTr + boff;
  const short* pxi = xnTi + boff;

  f32x4 accRa = {0.f,0.f,0.f,0.f}, accRb = {0.f,0.f,0.f,0.f}, accI = {0.f,0.f,0.f,0.f};
  #pragma unroll
  for (int kt = 0; kt < 320; kt += 32){
    short8_t wR = *(const short8_t*)(pwr + kt);
    short8_t wI = *(const short8_t*)(pwi + kt);
    short8_t xR = *(const short8_t*)(pxr + kt);
    short8_t xI = *(const short8_t*)(pxi + kt);
    accRa = __builtin_amdgcn_mfma_f32_16x16x32_bf16(wR, xR, accRa, 0,0,0);
    accRb = __builtin_amdgcn_mfma_f32_16x16x32_bf16(wI, xI, accRb, 0,0,0);
    accI  = __builtin_amdgcn_mfma_f32_16x16x32_bf16(wR, xI, accI, 0,0,0);
    accI  = __builtin_amdgcn_mfma_f32_16x16x32_bf16(wI, xR, accI, 0,0,0);
  }
  int col = l & 15, r0 = (l>>4)*4;
  #pragma unroll
  for (int r=0;r<4;r++){
    long o = (long)wid*204800 + (long)(i0+r0+r)*HH + j0+col;
    Ur[o] = bfr(accRa[r] - accRb[r]);
    Ui[o] = bfr(accI[r]);
  }
}

// ---------- GEMM4 (MFMA): Xos[(kx*640+ky)*NC+s] = U[s]·W2^T, bf16 out ----------
template<int NC>
__global__ __launch_bounds__(64*NC)
void cgemm4_mfma(const short* __restrict__ Ur, const short* __restrict__ Ui,
                 const short* __restrict__ Wr, const short* __restrict__ Wi,
                 unsigned* __restrict__ Xos)
{
  __shared__ unsigned sh[256*NC];
  int nwg = gridDim.x, orig = blockIdx.x;
  int qn = nwg>>3, rn = nwg&7;
  int xcd = orig&7, pos = orig>>3;
  int wg = (xcd<rn ? xcd*(qn+1) : rn*(qn+1)+(xcd-rn)*qn) + pos;
  int bj = wg % 40, bi = wg / 40;
  int i0 = bi*16, j0 = bj*16;
  int l = threadIdx.x & 63, wid = threadIdx.x >> 6;

  long aoff = (long)wid*204800 + (long)(i0 + (l&15))*HH + ((l>>4)<<3);
  const short* par = Ur + aoff;
  const short* pai = Ui + aoff;
  long boff = (long)(j0 + (l&15))*HH + ((l>>4)<<3);
  const short* pbr = Wr + boff;
  const short* pbi = Wi + boff;

  f32x4 accRa = {0.f,0.f,0.f,0.f}, accRb = {0.f,0.f,0.f,0.f}, accI = {0.f,0.f,0.f,0.f};
  #pragma unroll
  for (int kt = 0; kt < 320; kt += 32){
    short8_t aR = *(const short8_t*)(par + kt);
    short8_t aI = *(const short8_t*)(pai + kt);
    short8_t bR = *(const short8_t*)(pbr + kt);
    short8_t bI = *(const short8_t*)(pbi + kt);
    accRa = __builtin_amdgcn_mfma_f32_16x16x32_bf16(aR, bR, accRa, 0,0,0);
    accRb = __builtin_amdgcn_mfma_f32_16x16x32_bf16(aI, bI, accRb, 0,0,0);
    accI  = __builtin_amdgcn_mfma_f32_16x16x32_bf16(aR, bI, accI, 0,0,0);
    accI  = __builtin_amdgcn_mfma_f32_16x16x32_bf16(aI, bR, accI, 0,0,0);
  }

  int col = l & 15, r0 = (l>>4)*4;
  #pragma unroll
  for (int r=0;r<4;r++)
    sh[(r0+r)*16*NC + col*NC + wid] = pkbf(make_float2(accRa[r]-accRb[r], accI[r]));
  __syncthreads();

  int t = threadIdx.x;
  int row = t/(4*NC), q = t - row*(4*NC);
  uint4 v = ((const uint4*)(sh + row*16*NC))[q];
  ((uint4*)(Xos + ((long)(i0+row)*GG + j0)*NC))[q] = v;
}

// ---------- KB gather, row-split, shared wy, bf16 interleaved Xos ----------
template<int NC>
__global__ __launch_bounds__(384)
void interp6(const float* __restrict__ tkx, const float* __restrict__ tky,
             const unsigned* __restrict__ Xos, float* __restrict__ out,
             int slice0, int cplx, float beta, float inv_i0b){
  __shared__ float2 sh[NC][6][64];
  __shared__ float swy[6][64];
  int tid = threadIdx.x;
  int ptl = tid & 63;
  int jx  = tid >> 6;
  int p   = blockIdx.x*64 + ptl;   // 8000 blocks * 64 = 512000 exactly

  float gx = tkx[p]*2.0f, gy = tky[p]*2.0f;
  int ix0 = (int)floorf(gx) - 2;
  int iy0 = (int)floorf(gy) - 2;

  int ixu = ix0 + jx;
  int ixm = (ixu < 0) ? ixu + GG : ((ixu >= GG) ? ixu - GG : ixu);
  float wxj = kbw(gx - (float)ixu, beta, inv_i0b);
  swy[jx][ptl] = kbw(gy - (float)(iy0 + jx), beta, inv_i0b);

  int iym[6];
  #pragma unroll
  for (int j=0;j<6;j++){
    int iyu = iy0 + j;
    iym[j] = (iyu < 0) ? iyu + GG : ((iyu >= GG) ? iyu - GG : iyu);
  }
  __syncthreads();
  float wy[6];
  #pragma unroll
  for (int j=0;j<6;j++) wy[j] = swy[j][ptl];

  float2 acc[NC];
  #pragma unroll
  for (int s=0;s<NC;s++) acc[s] = make_float2(0.f, 0.f);

  const unsigned* rowp = Xos + (long)ixm*(GG*NC);
  #pragma unroll
  for (int jy=0;jy<6;jy++){
    float w = wy[jy];
    const unsigned* s2 = rowp + iym[jy]*NC;
    unsigned uu[NC];
    if constexpr (NC == 8){
      uint4 v0 = ((const uint4*)s2)[0], v1 = ((const uint4*)s2)[1];
      uu[0]=v0.x; uu[1]=v0.y; uu[2]=v0.z; uu[3]=v0.w;
      uu[4]=v1.x; uu[5]=v1.y; uu[6]=v1.z; uu[7]=v1.w;
    } else if constexpr (NC == 4){
      uint4 v = *(const uint4*)s2;
      uu[0]=v.x; uu[1]=v.y; uu[2]=v.z; uu[3]=v.w;
    } else if constexpr (NC == 2){
      uint2 v = *(const uint2*)s2;
      uu[0]=v.x; uu[1]=v.y;
    } else {
      uu[0] = s2[0];
    }
    #pragma unroll
    for (int s=0;s<NC;s++){
      float re = __uint_as_float(uu[s] << 16);
      float im = __uint_as_float(uu[s] & 0xffff0000u);
      acc[s].x = fmaf(w, re, acc[s].x);
      acc[s].y = fmaf(w, im, acc[s].y);
    }
  }
  #pragma unroll
  for (int s=0;s<NC;s++)
    sh[s][jx][ptl] = make_float2(acc[s].x*wxj, acc[s].y*wxj);
  __syncthreads();

  for (int t2 = tid; t2 < 64*NC; t2 += 384){
    int pt = t2 & 63;
    int s  = t2 >> 6;
    float2 r = make_float2(0.f, 0.f);
    #pragma unroll
    for (int j=0;j<6;j++){
      float2 v = sh[s][j][pt];
      r.x += v.x; r.y += v.y;
    }
    long pg = (long)blockIdx.x*64 + pt;
    if (cplx){
      ((float2*)out)[(long)(slice0+s)*PTS + pg] = r;
    } else {
      out[(long)(slice0+s)*PTS + pg] = r.x;
    }
  }
}

// ---------- launch ----------
extern "C" void kernel_launch(void* const* d_in, const int* in_sizes, int n_in,
                              void* d_out, int out_size, void* d_ws, size_t ws_size,
                              hipStream_t stream) {
  const float* kr  = (const float*)d_in[0];
  const float* ki  = (const float*)d_in[1];
  const float* tkx = (const float*)d_in[2];
  const float* tky = (const float*)d_in[3];
  char* ws = (char*)d_ws;

  // ---- workspace layout (bytes) ----
  short*  M1r   = (short*)(ws + 0);          //   204,800
  short*  M1i   = (short*)(ws + 204800);     //   204,800 ->   409,600
  short*  Wr    = (short*)(ws + 409600);     //   409,600 ->   819,200
  short*  Wi    = (short*)(ws + 819200);     //   409,600 -> 1,228,800
  float*  rap   = (float*) (ws + 1228800);   //     1,280 -> 1,230,080
  float4* stats = (float4*)(ws + 1230080);   //       128 -> 1,230,208
  double* part  = (double*)(ws + 1230208);   //     8,192 -> 1,238,400
  short*  Kr    = (short*)(ws + 1238400);    // 1,638,400 -> 2,876,800
  short*  Ki    = (short*)(ws + 2876800);    // 1,638,400 -> 4,515,200
  short*  Ttr   = (short*)(ws + 4515200);    // 1,638,400 -> 6,153,600
  short*  Tti   = (short*)(ws + 6153600);    // 1,638,400 -> 7,792,000
  float2* P     = (float2*)(ws + 7792000);   // 6,553,600 -> 14,345,600 (image f32)
  short*  xnTr  = (short*)(ws + 14345600);   // 1,638,400 -> 15,984,000
  short*  xnTi  = (short*)(ws + 15984000);   // 1,638,400 -> 17,622,400

  // nc ladder: Xos = nc*1,638,400 at 17,622,400; Ur/Ui overlay dead P region
  int nc = 1;
  if      (ws_size >= (size_t)(17622400 + 8L*1638400)) nc = 8;   // 30,729,600
  else if (ws_size >= (size_t)(17622400 + 4L*1638400)) nc = 4;
  else if (ws_size >= (size_t)(17622400 + 2L*1638400)) nc = 2;
  if (ws_size < (size_t)(17622400 + 1638400)) return;            // fail clean

  short*    Ur  = (short*)(ws + 7792000);                    // nc*409,600 (P dead after tnorm)
  short*    Ui  = (short*)(ws + 7792000 + (long)nc*409600);  // nc*409,600
  unsigned* Xos = (unsigned*)(ws + 17622400);                // nc*1,638,400

  int cplx = (out_size >= 8192000) ? 1 : 0;

  // host-side constants
  double beta_d = M_PI * sqrt(9.0*2.25 - 0.8);
  double qq = beta_d*beta_d/4.0, term = 1.0, i0b = 1.0;
  for (int k=1;k<64;k++){ term *= qq/((double)k*(double)k); i0b += term; }
  float beta = (float)beta_d;
  float inv_i0b = (float)(1.0/i0b);

  build_m1bf<<<400, 256, 0, stream>>>(M1r, M1i);
  build_w2  <<<800, 256, 0, stream>>>(Wr, Wi);
  build_rap <<<1,   320, 0, stream>>>(rap, beta);
  pack_bf   <<<3200,256, 0, stream>>>(kr, ki, Kr, Ki, NB*HH*HH);

  gemm1_mfma<<<400, 512, 0, stream>>>(M1r, M1i, Kr, Ki, Ttr, Tti);
  gemm2_mfma<<<400, 512, 0, stream>>>(M1r, M1i, Ttr, Tti, P);
  stats_part<<<dim3(32,NB), 256, 0, stream>>>(P, part);
  stats_fin <<<NB, 64, 0, stream>>>(part, stats);
  tnorm<<<dim3(10,10,NB), 256, 0, stream>>>(P, stats, rap, xnTr, xnTi);

  for (int c = 0; c < NB/nc; ++c){
    switch (nc){
      case 8:
        cgemm3_mfma<8><<<800, 512,0,stream>>>(Wr,Wi,xnTr,xnTi,Ur,Ui, c*8);
        cgemm4_mfma<8><<<1600,512,0,stream>>>(Ur,Ui,Wr,Wi,Xos);
        interp6<8><<<8000,384,0,stream>>>(tkx,tky,Xos,(float*)d_out, c*8, cplx, beta, inv_i0b);
        break;
      case 4:
        cgemm3_mfma<4><<<800, 256,0,stream>>>(Wr,Wi,xnTr,xnTi,Ur,Ui, c*4);
        cgemm4_mfma<4><<<1600,256,0,stream>>>(Ur,Ui,Wr,Wi,Xos);
        interp6<4><<<8000,384,0,stream>>>(tkx,tky,Xos,(float*)d_out, c*4, cplx, beta, inv_i0b);
        break;
      case 2:
        cgemm3_mfma<2><<<800, 128,0,stream>>>(Wr,Wi,xnTr,xnTi,Ur,Ui, c*2);
        cgemm4_mfma<2><<<1600,128,0,stream>>>(Ur,Ui,Wr,Wi,Xos);
        interp6<2><<<8000,384,0,stream>>>(tkx,tky,Xos,(float*)d_out, c*2, cplx, beta, inv_i0b);
        break;
      default:
        cgemm3_mfma<1><<<800,  64,0,stream>>>(Wr,Wi,xnTr,xnTi,Ur,Ui, c);
        cgemm4_mfma<1><<<1600, 64,0,stream>>>(Ur,Ui,Wr,Wi,Xos);
        interp6<1><<<8000,384,0,stream>>>(tkx,tky,Xos,(float*)d_out, c, cplx, beta, inv_i0b);
        break;
    }
  }
}

// Round 15
// 248.284 us; speedup vs baseline: 2.4608x; 1.2059x over previous
//
#include <hip/hip_runtime.h>
#include <math.h>

#ifndef M_PI
#define M_PI 3.14159265358979323846
#endif

// ---------- constants ----------
#define HH   320
#define GG   640
#define NB   8
#define PTS  512000   // 800 * 640

typedef __attribute__((ext_vector_type(8)))  short short8_t;
typedef __attribute__((ext_vector_type(4)))  float f32x4;
typedef __attribute__((ext_vector_type(16))) float f32x16;

// ---------- helpers ----------
__device__ __forceinline__ float bessel_i0f(float x){
  if (x < 3.75f){
    float t = (x*x) * (1.0f/(3.75f*3.75f));
    return 1.0f + t*(3.5156229f + t*(3.0899424f + t*(1.2067492f +
                 t*(0.2659732f + t*(0.0360768f + t*0.0045813f)))));
  } else {
    float t = 3.75f/x;
    float p = 0.39894228f + t*(0.01328592f + t*(0.00225319f + t*(-0.00157565f +
              t*(0.00916281f + t*(-0.02057706f + t*(0.02635537f +
              t*(-0.01647633f + t*0.00392377f)))))));
    return expf(x)*rsqrtf(x)*p;
  }
}

__device__ __forceinline__ float kbw(float d, float beta, float inv_i0b){
  float q = d * 0.33333333333333f;        // 2d/W with W=6
  float u = 1.0f - q*q;
  u = fmaxf(u, 0.0f);
  return bessel_i0f(beta * sqrtf(u)) * inv_i0b;
}

// f32 -> bf16 (RNE)
__device__ __forceinline__ short bfr(float x){
  unsigned u = __float_as_uint(x);
  u = (u + 0x7fffu + ((u>>16)&1u)) >> 16;
  return (short)u;
}
__device__ __forceinline__ float bf2f(short v){
  return __uint_as_float(((unsigned)(unsigned short)v) << 16);
}
// pack float2 -> complex bf16 (re low16, im high16), RNE
__device__ __forceinline__ unsigned pkbf(float2 v){
  unsigned a = __float_as_uint(v.x);
  a = (a + 0x7fffu + ((a>>16)&1u)) >> 16;
  unsigned b = __float_as_uint(v.y);
  b = (b + 0x7fffu + ((b>>16)&1u)) & 0xffff0000u;
  return a | b;
}

// ---------- fused builders: M1 planes | W2 planes | pack input | rap ----------
__global__ void build_all(const float* __restrict__ kr, const float* __restrict__ ki,
                          short* __restrict__ M1r, short* __restrict__ M1i,
                          short* __restrict__ Wr,  short* __restrict__ Wi,
                          float* __restrict__ rap,
                          short* __restrict__ Kr,  short* __restrict__ Ki,
                          float beta){
  int blk = blockIdx.x, tid = threadIdx.x;
  if (blk < 400){                      // M1[x][k], symmetric
    int idx = blk*256 + tid;
    if (idx >= HH*HH) return;
    int x = idx / HH, k = idx - x*HH;
    int r = (x*k) % HH;
    float ang = (float)r * (6.283185307179586f/(float)HH);
    float s, c; sincosf(ang, &s, &c);
    float sg = ((x + k) & 1) ? -0.05590169943749474f : 0.05590169943749474f;
    M1r[idx] = bfr(sg*c);
    M1i[idx] = bfr(sg*s);
  } else if (blk < 1200){              // W2[k][m]
    int idx = (blk-400)*256 + tid;
    if (idx >= GG*HH) return;
    int k = idx / HH, m = idx - k*HH;
    int t = (k * (m - 160)) % GG; if (t < 0) t += GG;
    float ang = (float)t * (6.283185307179586f/(float)GG);
    float s, c; sincosf(ang, &s, &c);
    Wr[idx] = bfr(c);
    Wi[idx] = bfr(-s);
  } else if (blk < 4400){              // pack input k-space
    int idx = (blk-1200)*256 + tid;
    if (idx >= NB*HH*HH) return;
    Kr[idx] = bfr(kr[idx]);
    Ki[idx] = bfr(ki[idx]);
  } else {                             // rap
    for (int n = tid; n < HH; n += 256){
      float f = (float)(n - 160) * (1.0f/(float)GG);
      float w = 3.14159265358979f * 6.0f * f;
      float t = beta*beta - w*w;
      float z = fmaxf(sqrtf(fabsf(t)), 1e-7f);
      float a = (t > 0.0f ? sinhf(z) : sinf(z)) / z;
      float a0 = sinhf(beta) / beta;
      rap[n] = a0 / a;
    }
  }
}

// ---------- GEMM1 (MFMA 16x16): Tt[b][j][i] = sum_k M1[j][k] * Kc[b][i][k] ----------
__global__ __launch_bounds__(512)
void gemm1_mfma(const short* __restrict__ M1r, const short* __restrict__ M1i,
                const short* __restrict__ Kr,  const short* __restrict__ Ki,
                short* __restrict__ Ttr, short* __restrict__ Tti)
{
  int nwg = gridDim.x, orig = blockIdx.x;
  int qn = nwg>>3, rn = nwg&7;
  int xcd = orig&7, pos = orig>>3;
  int wg = (xcd<rn ? xcd*(qn+1) : rn*(qn+1)+(xcd-rn)*qn) + pos;
  int ti = wg % 20, tj = wg / 20;
  int i0 = ti*16, j0 = tj*16;
  int l = threadIdx.x & 63, wid = threadIdx.x >> 6;

  long aoff = (long)(j0 + (l&15))*HH + ((l>>4)<<3);       // M1 row j
  const short* pmr = M1r + aoff;
  const short* pmi = M1i + aoff;
  long boff = (long)wid*102400 + (long)(i0 + (l&15))*HH + ((l>>4)<<3);  // Kc row i
  const short* pkr = Kr + boff;
  const short* pki = Ki + boff;

  f32x4 accRa = {0.f,0.f,0.f,0.f}, accRb = {0.f,0.f,0.f,0.f}, accI = {0.f,0.f,0.f,0.f};
  #pragma unroll
  for (int kt = 0; kt < 320; kt += 32){
    short8_t mR = *(const short8_t*)(pmr + kt);
    short8_t mI = *(const short8_t*)(pmi + kt);
    short8_t kR = *(const short8_t*)(pkr + kt);
    short8_t kI = *(const short8_t*)(pki + kt);
    accRa = __builtin_amdgcn_mfma_f32_16x16x32_bf16(mR, kR, accRa, 0,0,0);
    accRb = __builtin_amdgcn_mfma_f32_16x16x32_bf16(mI, kI, accRb, 0,0,0);
    accI  = __builtin_amdgcn_mfma_f32_16x16x32_bf16(mR, kI, accI, 0,0,0);
    accI  = __builtin_amdgcn_mfma_f32_16x16x32_bf16(mI, kR, accI, 0,0,0);
  }
  int col = l & 15, r0 = (l>>4)*4;
  #pragma unroll
  for (int r=0;r<4;r++){
    long o = (long)wid*102400 + (long)(j0+r0+r)*HH + i0+col;
    Ttr[o] = bfr(accRa[r] - accRb[r]);
    Tti[o] = bfr(accI[r]);
  }
}

// ---------- GEMM2 (MFMA 16x16) + fused stats: image bf16 planes + f64 partials ----------
__global__ __launch_bounds__(512)
void gemm2_mfma(const short* __restrict__ M1r, const short* __restrict__ M1i,
                const short* __restrict__ Ttr, const short* __restrict__ Tti,
                short* __restrict__ Pr, short* __restrict__ Pi,
                double* __restrict__ part)
{
  int nwg = gridDim.x, orig = blockIdx.x;
  int qn = nwg>>3, rn = nwg&7;
  int xcd = orig&7, pos = orig>>3;
  int wg = (xcd<rn ? xcd*(qn+1) : rn*(qn+1)+(xcd-rn)*qn) + pos;
  int tj = wg % 20, ti = wg / 20;
  int i0 = ti*16, j0 = tj*16;
  int l = threadIdx.x & 63, wid = threadIdx.x >> 6;

  long aoff = (long)(i0 + (l&15))*HH + ((l>>4)<<3);       // M1 row i
  const short* pmr = M1r + aoff;
  const short* pmi = M1i + aoff;
  long boff = (long)wid*102400 + (long)(j0 + (l&15))*HH + ((l>>4)<<3);  // Tt row j
  const short* ptr = Ttr + boff;
  const short* pti = Tti + boff;

  f32x4 accRa = {0.f,0.f,0.f,0.f}, accRb = {0.f,0.f,0.f,0.f}, accI = {0.f,0.f,0.f,0.f};
  #pragma unroll
  for (int kt = 0; kt < 320; kt += 32){
    short8_t mR = *(const short8_t*)(pmr + kt);
    short8_t mI = *(const short8_t*)(pmi + kt);
    short8_t tR = *(const short8_t*)(ptr + kt);
    short8_t tI = *(const short8_t*)(pti + kt);
    accRa = __builtin_amdgcn_mfma_f32_16x16x32_bf16(mR, tR, accRa, 0,0,0);
    accRb = __builtin_amdgcn_mfma_f32_16x16x32_bf16(mI, tI, accRb, 0,0,0);
    accI  = __builtin_amdgcn_mfma_f32_16x16x32_bf16(mR, tI, accI, 0,0,0);
    accI  = __builtin_amdgcn_mfma_f32_16x16x32_bf16(mI, tR, accI, 0,0,0);
  }
  int col = l & 15, r0 = (l>>4)*4;
  float sr=0.f, si=0.f, srr=0.f, sii=0.f;
  #pragma unroll
  for (int r=0;r<4;r++){
    float re = accRa[r] - accRb[r];
    float im = accI[r];
    long o = (long)wid*102400 + (long)(i0+r0+r)*HH + j0+col;
    Pr[o] = bfr(re);
    Pi[o] = bfr(im);
    sr += re; si += im; srr += re*re; sii += im*im;
  }
  // exact f64 wave reduce of this wave's 16x16 tile (slice = wid)
  double d0 = sr, d1 = si, d2 = srr, d3 = sii;
  #pragma unroll
  for (int off = 32; off > 0; off >>= 1){
    d0 += __shfl_down(d0, off);
    d1 += __shfl_down(d1, off);
    d2 += __shfl_down(d2, off);
    d3 += __shfl_down(d3, off);
  }
  if (l == 0){
    long pidx = ((long)wid*400 + wg)*4;
    part[pidx  ] = d0;
    part[pidx+1] = d1;
    part[pidx+2] = d2;
    part[pidx+3] = d3;
  }
}

// ---------- stats finish (ddof=1) over 400 tile-partials per slice ----------
__global__ void stats_fin(const double* __restrict__ part, float4* __restrict__ stats){
  int b = blockIdx.x;
  int t = threadIdx.x;  // 256
  __shared__ double sh[256];
  double loc[4] = {0.0,0.0,0.0,0.0};
  for (int w = t; w < 400; w += 256){
    const double* p = part + ((long)b*400 + w)*4;
    loc[0] += p[0]; loc[1] += p[1]; loc[2] += p[2]; loc[3] += p[3];
  }
  double red[4];
  #pragma unroll
  for (int q=0;q<4;q++){
    sh[t] = loc[q];
    __syncthreads();
    for (int s=128; s>0; s>>=1){
      if (t < s) sh[t] += sh[t + s];
      __syncthreads();
    }
    red[q] = sh[0];
    __syncthreads();
  }
  if (t == 0){
    double N = (double)(HH*HH);
    double mr = red[0]/N, mi = red[1]/N;
    double vr = (red[2] - N*mr*mr)/(N-1.0);
    double vi = (red[3] - N*mi*mi)/(N-1.0);
    stats[b] = make_float4((float)mr, (float)mi,
                           (float)(1.0/sqrt(vr)), (float)(1.0/sqrt(vi)));
  }
}

// ---------- normalize + apod + TRANSPOSE (bf16 planes in -> bf16 planes out) ----------
__global__ __launch_bounds__(256)
void tnorm(const short* __restrict__ Pr, const short* __restrict__ Pi,
           const float4* __restrict__ stats, const float* __restrict__ rap,
           short* __restrict__ xnTr, short* __restrict__ xnTi){
  __shared__ float2 tile[32][33];
  int b = blockIdx.z;
  int i0 = blockIdx.y*32, j0 = blockIdx.x*32;
  int tx = threadIdx.x & 31, ty = threadIdx.x >> 5;  // 32 x 8
  float4 st = stats[b];
  #pragma unroll
  for (int r=0;r<4;r++){
    int i = i0 + ty + r*8, j = j0 + tx;
    long o = (long)b*102400 + (long)i*HH + j;
    float re = bf2f(Pr[o]), im = bf2f(Pi[o]);
    float sc = rap[i]*rap[j];
    tile[ty+r*8][tx] = make_float2((re-st.x)*st.z*sc, (im-st.y)*st.w*sc);
  }
  __syncthreads();
  #pragma unroll
  for (int r=0;r<4;r++){
    int j = j0 + ty + r*8, i = i0 + tx;
    float2 v = tile[tx][ty+r*8];
    long o = (long)b*102400 + (long)j*HH + i;
    xnTr[o] = bfr(v.x);
    xnTi[o] = bfr(v.y);
  }
}

// ---------- GEMM3 (MFMA 32x32x16): U[s][kx][j] = sum_m W2[kx][m] * xnT[s][j][m] ----------
// Wave = one 32x32 tile of slice wid; grid 20(kx) x 10(j) = 200 blocks.
template<int NC>
__global__ __launch_bounds__(64*NC)
void cgemm3_mfma(const short* __restrict__ Wr, const short* __restrict__ Wi,
                 const short* __restrict__ xnTr, const short* __restrict__ xnTi,
                 short* __restrict__ Ur, short* __restrict__ Ui, int slice0)
{
  int nwg = gridDim.x, orig = blockIdx.x;
  int qn = nwg>>3, rn = nwg&7;
  int xcd = orig&7, pos = orig>>3;
  int wg = (xcd<rn ? xcd*(qn+1) : rn*(qn+1)+(xcd-rn)*qn) + pos;
  int bj = wg % 10, bi = wg / 10;
  int i0 = bi*32, j0 = bj*32;
  int l = threadIdx.x & 63, wid = threadIdx.x >> 6;

  // A frag (32x32x16): row = l&31, k = (l>>5)*8 + j
  long aoff = (long)(i0 + (l&31))*HH + ((l>>5)<<3);
  const short* pwr = Wr + aoff;
  const short* pwi = Wi + aoff;
  long boff = (long)(slice0+wid)*102400 + (long)(j0 + (l&31))*HH + ((l>>5)<<3);
  const short* pxr = xnTr + boff;
  const short* pxi = xnTi + boff;

  f32x16 accRa = {0.f}, accRb = {0.f}, accI = {0.f};
  #pragma unroll
  for (int kt = 0; kt < 320; kt += 16){
    short8_t wR = *(const short8_t*)(pwr + kt);
    short8_t wI = *(const short8_t*)(pwi + kt);
    short8_t xR = *(const short8_t*)(pxr + kt);
    short8_t xI = *(const short8_t*)(pxi + kt);
    accRa = __builtin_amdgcn_mfma_f32_32x32x16_bf16(wR, xR, accRa, 0,0,0);
    accRb = __builtin_amdgcn_mfma_f32_32x32x16_bf16(wI, xI, accRb, 0,0,0);
    accI  = __builtin_amdgcn_mfma_f32_32x32x16_bf16(wR, xI, accI, 0,0,0);
    accI  = __builtin_amdgcn_mfma_f32_32x32x16_bf16(wI, xR, accI, 0,0,0);
  }
  // C/D 32x32: col = l&31, row = (r&3) + 8*(r>>2) + 4*(l>>5)  [m74/m101]
  int col = l & 31, rhi = 4*(l>>5);
  #pragma unroll
  for (int r=0;r<16;r++){
    int row = (r&3) + 8*(r>>2) + rhi;
    long o = (long)wid*204800 + (long)(i0+row)*HH + j0+col;
    Ur[o] = bfr(accRa[r] - accRb[r]);
    Ui[o] = bfr(accI[r]);
  }
}

// ---------- GEMM4 (MFMA 32x32x16): Xos[(kx*640+ky)*NC+s] = U[s]·W2^T ----------
// Wave = one 32x32 tile of slice wid; grid 20x20 = 400 blocks.
template<int NC>
__global__ __launch_bounds__(64*NC)
void cgemm4_mfma(const short* __restrict__ Ur, const short* __restrict__ Ui,
                 const short* __restrict__ Wr, const short* __restrict__ Wi,
                 unsigned* __restrict__ Xos)
{
  __shared__ unsigned sh[1024*NC];   // [row 32][col 32][NC]
  int nwg = gridDim.x, orig = blockIdx.x;
  int qn = nwg>>3, rn = nwg&7;
  int xcd = orig&7, pos = orig>>3;
  int wg = (xcd<rn ? xcd*(qn+1) : rn*(qn+1)+(xcd-rn)*qn) + pos;
  int bj = wg % 20, bi = wg / 20;
  int i0 = bi*32, j0 = bj*32;
  int l = threadIdx.x & 63, wid = threadIdx.x >> 6;

  long aoff = (long)wid*204800 + (long)(i0 + (l&31))*HH + ((l>>5)<<3);
  const short* par = Ur + aoff;
  const short* pai = Ui + aoff;
  long boff = (long)(j0 + (l&31))*HH + ((l>>5)<<3);
  const short* pbr = Wr + boff;
  const short* pbi = Wi + boff;

  f32x16 accRa = {0.f}, accRb = {0.f}, accI = {0.f};
  #pragma unroll
  for (int kt = 0; kt < 320; kt += 16){
    short8_t aR = *(const short8_t*)(par + kt);
    short8_t aI = *(const short8_t*)(pai + kt);
    short8_t bR = *(const short8_t*)(pbr + kt);
    short8_t bI = *(const short8_t*)(pbi + kt);
    accRa = __builtin_amdgcn_mfma_f32_32x32x16_bf16(aR, bR, accRa, 0,0,0);
    accRb = __builtin_amdgcn_mfma_f32_32x32x16_bf16(aI, bI, accRb, 0,0,0);
    accI  = __builtin_amdgcn_mfma_f32_32x32x16_bf16(aR, bI, accI, 0,0,0);
    accI  = __builtin_amdgcn_mfma_f32_32x32x16_bf16(aI, bR, accI, 0,0,0);
  }

  int col = l & 31, rhi = 4*(l>>5);
  #pragma unroll
  for (int r=0;r<16;r++){
    int row = (r&3) + 8*(r>>2) + rhi;
    sh[row*32*NC + col*NC + wid] = pkbf(make_float2(accRa[r]-accRb[r], accI[r]));
  }
  __syncthreads();

  // dense write: 32 rows x (32*NC) uints; per-row 8*NC uint4
  int tid = threadIdx.x;
  #pragma unroll
  for (int q=0;q<4;q++){
    int idx = tid + 64*NC*q;            // < 256*NC
    int row = idx / (8*NC);
    int w   = idx - row*(8*NC);
    uint4 v = ((const uint4*)(sh + row*32*NC))[w];
    ((uint4*)(Xos + ((long)(i0+row)*GG + j0)*NC))[w] = v;
  }
}

// ---------- KB gather, row-split, shared wy, bf16 interleaved Xos ----------
template<int NC>
__global__ __launch_bounds__(384)
void interp6(const float* __restrict__ tkx, const float* __restrict__ tky,
             const unsigned* __restrict__ Xos, float* __restrict__ out,
             int slice0, int cplx, float beta, float inv_i0b){
  __shared__ float2 sh[NC][6][64];
  __shared__ float swy[6][64];
  int tid = threadIdx.x;
  int ptl = tid & 63;
  int jx  = tid >> 6;
  int p   = blockIdx.x*64 + ptl;   // 8000 blocks * 64 = 512000 exactly

  float gx = tkx[p]*2.0f, gy = tky[p]*2.0f;
  int ix0 = (int)floorf(gx) - 2;
  int iy0 = (int)floorf(gy) - 2;

  int ixu = ix0 + jx;
  int ixm = (ixu < 0) ? ixu + GG : ((ixu >= GG) ? ixu - GG : ixu);
  float wxj = kbw(gx - (float)ixu, beta, inv_i0b);
  swy[jx][ptl] = kbw(gy - (float)(iy0 + jx), beta, inv_i0b);

  int iym[6];
  #pragma unroll
  for (int j=0;j<6;j++){
    int iyu = iy0 + j;
    iym[j] = (iyu < 0) ? iyu + GG : ((iyu >= GG) ? iyu - GG : iyu);
  }
  __syncthreads();
  float wy[6];
  #pragma unroll
  for (int j=0;j<6;j++) wy[j] = swy[j][ptl];

  float2 acc[NC];
  #pragma unroll
  for (int s=0;s<NC;s++) acc[s] = make_float2(0.f, 0.f);

  const unsigned* rowp = Xos + (long)ixm*(GG*NC);
  #pragma unroll
  for (int jy=0;jy<6;jy++){
    float w = wy[jy];
    const unsigned* s2 = rowp + iym[jy]*NC;
    unsigned uu[NC];
    if constexpr (NC == 8){
      uint4 v0 = ((const uint4*)s2)[0], v1 = ((const uint4*)s2)[1];
      uu[0]=v0.x; uu[1]=v0.y; uu[2]=v0.z; uu[3]=v0.w;
      uu[4]=v1.x; uu[5]=v1.y; uu[6]=v1.z; uu[7]=v1.w;
    } else if constexpr (NC == 4){
      uint4 v = *(const uint4*)s2;
      uu[0]=v.x; uu[1]=v.y; uu[2]=v.z; uu[3]=v.w;
    } else if constexpr (NC == 2){
      uint2 v = *(const uint2*)s2;
      uu[0]=v.x; uu[1]=v.y;
    } else {
      uu[0] = s2[0];
    }
    #pragma unroll
    for (int s=0;s<NC;s++){
      float re = __uint_as_float(uu[s] << 16);
      float im = __uint_as_float(uu[s] & 0xffff0000u);
      acc[s].x = fmaf(w, re, acc[s].x);
      acc[s].y = fmaf(w, im, acc[s].y);
    }
  }
  #pragma unroll
  for (int s=0;s<NC;s++)
    sh[s][jx][ptl] = make_float2(acc[s].x*wxj, acc[s].y*wxj);
  __syncthreads();

  for (int t2 = tid; t2 < 64*NC; t2 += 384){
    int pt = t2 & 63;
    int s  = t2 >> 6;
    float2 r = make_float2(0.f, 0.f);
    #pragma unroll
    for (int j=0;j<6;j++){
      float2 v = sh[s][j][pt];
      r.x += v.x; r.y += v.y;
    }
    long pg = (long)blockIdx.x*64 + pt;
    if (cplx){
      ((float2*)out)[(long)(slice0+s)*PTS + pg] = r;
    } else {
      out[(long)(slice0+s)*PTS + pg] = r.x;
    }
  }
}

// ---------- launch ----------
extern "C" void kernel_launch(void* const* d_in, const int* in_sizes, int n_in,
                              void* d_out, int out_size, void* d_ws, size_t ws_size,
                              hipStream_t stream) {
  const float* kr  = (const float*)d_in[0];
  const float* ki  = (const float*)d_in[1];
  const float* tkx = (const float*)d_in[2];
  const float* tky = (const float*)d_in[3];
  char* ws = (char*)d_ws;

  // ---- workspace layout (bytes) ----
  short*  M1r   = (short*)(ws + 0);          //   204,800
  short*  M1i   = (short*)(ws + 204800);     //   204,800 ->   409,600
  short*  Wr    = (short*)(ws + 409600);     //   409,600 ->   819,200
  short*  Wi    = (short*)(ws + 819200);     //   409,600 -> 1,228,800
  float*  rap   = (float*) (ws + 1228800);   //     1,280 -> 1,230,080
  float4* stats = (float4*)(ws + 1230080);   //       128 -> 1,230,208
  double* part  = (double*)(ws + 1230208);   //   102,400 -> 1,332,608
  short*  Kr    = (short*)(ws + 1332608);    // 1,638,400 -> 2,971,008
  short*  Ki    = (short*)(ws + 2971008);    // 1,638,400 -> 4,609,408
  short*  Ttr   = (short*)(ws + 4609408);    // 1,638,400 -> 6,247,808
  short*  Tti   = (short*)(ws + 6247808);    // 1,638,400 -> 7,886,208
  short*  Pr    = (short*)(ws + 7886208);    // 1,638,400 -> 9,524,608
  short*  Pi    = (short*)(ws + 9524608);    // 1,638,400 -> 11,163,008
  short*  xnTr  = (short*)(ws + 11163008);   // 1,638,400 -> 12,801,408
  short*  xnTi  = (short*)(ws + 12801408);   // 1,638,400 -> 14,439,808

  int nc = 1;
  if      (ws_size >= (size_t)(14439808 + 8L*1638400)) nc = 8;   // 27,547,008
  else if (ws_size >= (size_t)(14439808 + 4L*1638400)) nc = 4;
  else if (ws_size >= (size_t)(14439808 + 2L*1638400)) nc = 2;
  if (ws_size < (size_t)(14439808 + 1638400)) return;            // fail clean

  // Ur/Ui overlay Kr..Tti (dead after gemm2); Xos after xnT planes
  short*    Ur  = (short*)(ws + 1332608);
  short*    Ui  = (short*)(ws + 1332608 + (long)nc*409600);
  unsigned* Xos = (unsigned*)(ws + 14439808);

  int cplx = (out_size >= 8192000) ? 1 : 0;

  // host-side constants
  double beta_d = M_PI * sqrt(9.0*2.25 - 0.8);
  double qq = beta_d*beta_d/4.0, term = 1.0, i0b = 1.0;
  for (int k=1;k<64;k++){ term *= qq/((double)k*(double)k); i0b += term; }
  float beta = (float)beta_d;
  float inv_i0b = (float)(1.0/i0b);

  build_all<<<4401, 256, 0, stream>>>(kr, ki, M1r, M1i, Wr, Wi, rap, Kr, Ki, beta);

  gemm1_mfma<<<400, 512, 0, stream>>>(M1r, M1i, Kr, Ki, Ttr, Tti);
  gemm2_mfma<<<400, 512, 0, stream>>>(M1r, M1i, Ttr, Tti, Pr, Pi, part);
  stats_fin <<<NB, 256, 0, stream>>>(part, stats);
  tnorm<<<dim3(10,10,NB), 256, 0, stream>>>(Pr, Pi, stats, rap, xnTr, xnTi);

  for (int c = 0; c < NB/nc; ++c){
    switch (nc){
      case 8:
        cgemm3_mfma<8><<<200, 512,0,stream>>>(Wr,Wi,xnTr,xnTi,Ur,Ui, c*8);
        cgemm4_mfma<8><<<400, 512,0,stream>>>(Ur,Ui,Wr,Wi,Xos);
        interp6<8><<<8000,384,0,stream>>>(tkx,tky,Xos,(float*)d_out, c*8, cplx, beta, inv_i0b);
        break;
      case 4:
        cgemm3_mfma<4><<<200, 256,0,stream>>>(Wr,Wi,xnTr,xnTi,Ur,Ui, c*4);
        cgemm4_mfma<4><<<400, 256,0,stream>>>(Ur,Ui,Wr,Wi,Xos);
        interp6<4><<<8000,384,0,stream>>>(tkx,tky,Xos,(float*)d_out, c*4, cplx, beta, inv_i0b);
        break;
      case 2:
        cgemm3_mfma<2><<<200, 128,0,stream>>>(Wr,Wi,xnTr,xnTi,Ur,Ui, c*2);
        cgemm4_mfma<2><<<400, 128,0,stream>>>(Ur,Ui,Wr,Wi,Xos);
        interp6<2><<<8000,384,0,stream>>>(tkx,tky,Xos,(float*)d_out, c*2, cplx, beta, inv_i0b);
        break;
      default:
        cgemm3_mfma<1><<<200,  64,0,stream>>>(Wr,Wi,xnTr,xnTi,Ur,Ui, c);
        cgemm4_mfma<1><<<400,  64,0,stream>>>(Ur,Ui,Wr,Wi,Xos);
        interp6<1><<<8000,384,0,stream>>>(tkx,tky,Xos,(float*)d_out, c, cplx, beta, inv_i0b);
        break;
    }
  }
}